// Round 9
// baseline (457.058 us; speedup 1.0000x reference)
//
#include <hip/hip_runtime.h>
#include <hip/hip_bf16.h>

// DeepSeek V3 MLA attention forward, MI355X (gfx950).
// B=2, S=2048, D=2048, H=16, NOPE=128, ROPE=64, VDIM=128, QKD=192.

typedef __bf16 bf16x8 __attribute__((ext_vector_type(8)));
typedef float floatx4 __attribute__((ext_vector_type(4)));
#define BF16 __hip_bfloat16

static __device__ __forceinline__ BF16 f2b(float x) { return __float2bfloat16(x); }
static __device__ __forceinline__ unsigned short b2u(BF16 x) { return *(unsigned short*)&x; }
static __device__ __forceinline__ float fast_exp2(float x) { return __builtin_amdgcn_exp2f(x); }

// DPP cross-lane move within a 16-lane row (VALU pipe, ~8 cyc vs ~60+ for ds_swizzle).
template<int CTRL>
static __device__ __forceinline__ float dpp_mov(float x) {
  int xi = __builtin_bit_cast(int, x);
  int yi = __builtin_amdgcn_update_dpp(xi, xi, CTRL, 0xF, 0xF, false);
  return __builtin_bit_cast(float, yi);
}
// all-reduce across the 16 lanes of a DPP row: quad xor1, quad xor2, half-mirror, mirror
static __device__ __forceinline__ float row_allmax(float x) {
  x = fmaxf(x, dpp_mov<0xB1>(x));   // quad_perm [1,0,3,2]
  x = fmaxf(x, dpp_mov<0x4E>(x));   // quad_perm [2,3,0,1]
  x = fmaxf(x, dpp_mov<0x141>(x));  // row_half_mirror
  x = fmaxf(x, dpp_mov<0x140>(x));  // row_mirror
  return x;
}
static __device__ __forceinline__ float row_allsum(float x) {
  x += dpp_mov<0xB1>(x);
  x += dpp_mov<0x4E>(x);
  x += dpp_mov<0x141>(x);
  x += dpp_mov<0x140>(x);
  return x;
}

static __device__ __forceinline__ void load_lds16(const BF16* g, BF16* l) {
  __builtin_amdgcn_global_load_lds((__attribute__((address_space(1))) void*)(void*)g,
                                   (__attribute__((address_space(3))) void*)(void*)l,
                                   16, 0, 0);
}

// ---------------------------------------------------------------- multi-region cast f32->bf16
struct CastArgs {
  const float* src[6];
  BF16* dst[6];
  long n[6];
};
__global__ void cast_multi_k(CastArgs a) {
  int r = blockIdx.y;
  long n = a.n[r];
  const float* __restrict__ x = a.src[r];
  BF16* __restrict__ y = a.dst[r];
  for (long i = ((long)blockIdx.x * 256 + threadIdx.x) * 4; i + 3 < n;
       i += (long)gridDim.x * 1024) {
    float4 v = *(const float4*)(x + i);
    y[i+0] = f2b(v.x); y[i+1] = f2b(v.y); y[i+2] = f2b(v.z); y[i+3] = f2b(v.w);
  }
}

// ---------------------------------------------------------------- NT GEMM v2
// C[M][N] = A[M][K]*B[N][K]^T.  256x128 tile, BK=64, 512 thr = 8 waves (4x2),
// per-wave 64x64 output (acc[4][4]).  Double-buffered LDS (96 KB),
// global_load_lds staging with XOR-swizzled source (T2), raw s_barrier +
// counted s_waitcnt vmcnt(6) pipeline (T4), s_setprio around MFMA (T5).
// OUT_MODE: 0 = fp32 C;  2 = kv scatter -> Kt (scalar) / Vt transposed (8B packed);
//           3 = q RoPE+scale scatter -> Qt (scale includes log2(e) for exp2 softmax).
template<int OUT_MODE>
static __device__ __forceinline__ void gemm_body(
    const BF16* __restrict__ A, const BF16* __restrict__ B, void* __restrict__ C,
    int M, int N, int K, const float* __restrict__ cosb, const float* __restrict__ sinb,
    BF16* __restrict__ P1, BF16* __restrict__ P2, int bx, int by, BF16* As, BF16* Bs) {
  int tid = threadIdx.x, wave = tid >> 6, lane = tid & 63;
  int wr = wave >> 1, wc = wave & 1, lr = lane & 15, quad = lane >> 4;
  long m0 = (long)by * 256, n0 = (long)bx * 128;

  // --- staging descriptors: per thread per K-tile, A = 4 chunks, B = 2 chunks (16B each).
  // chunk c -> tile row r = c>>3, chunk col k = c&7. LDS linear (r,k) receives
  // global chunk (r, k ^ (r&7)) so swizzled reads recover logical columns.
  long asrc[4]; int adst[4];
#pragma unroll
  for (int i = 0; i < 4; i++) {
    int c = wave*64 + lane + 512*i;
    int r = c >> 3, k = c & 7;
    asrc[i] = (m0 + r) * (long)K + ((k ^ (r & 7)) << 3);
    adst[i] = wave*512 + i*4096;          // wave-uniform LDS base (HW adds lane*16B)
  }
  long bsrc[2]; int bdst[2];
#pragma unroll
  for (int i = 0; i < 2; i++) {
    int c = wave*64 + lane + 512*i;
    int r = c >> 3, k = c & 7;
    long bn = n0 + r; if (bn >= N) bn = N - 1;  // N-tail clamp (stores are guarded)
    bsrc[i] = bn * (long)K + ((k ^ (r & 7)) << 3);
    bdst[i] = wave*512 + i*4096;
  }

  auto stage = [&](int bi, int kt) {   // 6 global_load_lds per wave per call
    long k0 = (long)kt << 6;
    BF16* Ad = As + bi*16384;
    BF16* Bd = Bs + bi*8192;
#pragma unroll
    for (int i = 0; i < 4; i++) load_lds16(A + asrc[i] + k0, Ad + adst[i]);
#pragma unroll
    for (int i = 0; i < 2; i++) load_lds16(B + bsrc[i] + k0, Bd + bdst[i]);
  };

  // --- read offsets (row*64 elems; chunk col XORed with row&7 = lr&7)
  int aoff[4], boff[4];
#pragma unroll
  for (int i = 0; i < 4; i++) aoff[i] = (wr*64 + i*16 + lr) * 64;
#pragma unroll
  for (int j = 0; j < 4; j++) boff[j] = (wc*64 + j*16 + lr) * 64;
  int x0 = ((quad    ) ^ (lr & 7)) << 3;   // kk=0: chunks 0..3
  int x1 = ((quad ^ 4) ^ (lr & 7)) << 3;   // kk=1: chunks 4..7

  floatx4 acc[4][4] = {};
  int NT = K >> 6;

  // prologue: stage tiles 0 and 1, wait only tile 0 (12 in flight -> 6)
  stage(0, 0);
  stage(1, 1);
  asm volatile("s_waitcnt vmcnt(6)" ::: "memory");
  __builtin_amdgcn_s_barrier();

  int cur = 0;
  for (int t = 0; t < NT; t++) {
    const BF16* Ab = As + cur*16384;
    const BF16* Bb = Bs + cur*8192;
    bf16x8 a0[4], a1[4], b0[4], b1[4];
#pragma unroll
    for (int i = 0; i < 4; i++) {
      a0[i] = *(const bf16x8*)(Ab + aoff[i] + x0);
      a1[i] = *(const bf16x8*)(Ab + aoff[i] + x1);
    }
#pragma unroll
    for (int j = 0; j < 4; j++) {
      b0[j] = *(const bf16x8*)(Bb + boff[j] + x0);
      b1[j] = *(const bf16x8*)(Bb + boff[j] + x1);
    }
    // all fragments in regs -> buf[cur] is free for restaging after this barrier
    asm volatile("s_waitcnt lgkmcnt(0)" ::: "memory");
    __builtin_amdgcn_s_barrier();
    if (t + 2 < NT) stage(cur, t + 2);   // issue-early: latency hides under MFMA
    __builtin_amdgcn_s_setprio(1);
#pragma unroll
    for (int i = 0; i < 4; i++)
#pragma unroll
      for (int j = 0; j < 4; j++)
        acc[i][j] = __builtin_amdgcn_mfma_f32_16x16x32_bf16(a0[i], b0[j], acc[i][j], 0, 0, 0);
#pragma unroll
    for (int i = 0; i < 4; i++)
#pragma unroll
      for (int j = 0; j < 4; j++)
        acc[i][j] = __builtin_amdgcn_mfma_f32_16x16x32_bf16(a1[i], b1[j], acc[i][j], 0, 0, 0);
    __builtin_amdgcn_s_setprio(0);
    // retire tile t+1's 6 loads (t+2's 6 stay in flight); publish via barrier
    if (t + 2 < NT)      { asm volatile("s_waitcnt vmcnt(6)" ::: "memory"); }
    else if (t + 1 < NT) { asm volatile("s_waitcnt vmcnt(0)" ::: "memory"); }
    __builtin_amdgcn_s_barrier();
    __builtin_amdgcn_sched_barrier(0);
    cur ^= 1;
  }

  long n0w = n0 + wc*64;
  // 192^-0.5 * log2(e): softmax runs in exp2 domain.
  const float SCALE_L2E = 0.104117546f;
#pragma unroll
  for (int i = 0; i < 4; i++) {
    long tok = m0 + wr*64 + i*16 + quad*4;   // 4 consecutive tokens (r=0..3)
    long bb = tok >> 11, s = tok & 2047;
    if (OUT_MODE == 0) {
#pragma unroll
      for (int r = 0; r < 4; r++) {
        long row = tok + r;
#pragma unroll
        for (int j = 0; j < 4; j++) {
          long col = n0w + j*16 + lr;
          if (col < N) ((float*)C)[row*(long)N + col] = acc[i][j][r];
        }
      }
    } else if (OUT_MODE == 2) {
#pragma unroll
      for (int j = 0; j < 4; j++) {
        long col = n0w + j*16 + lr;
        long h = col >> 8, d = col & 255;
        if (d < 128) {
#pragma unroll
          for (int r = 0; r < 4; r++)
            P1[((bb*16 + h)*2048 + s + r)*192 + d] = f2b(acc[i][j][r]);
        } else {
          // Vt transposed (B,H,128,2048): 4 consecutive tokens packed, 8B store
          ushort4 pk;
          pk.x = b2u(f2b(acc[i][j][0])); pk.y = b2u(f2b(acc[i][j][1]));
          pk.z = b2u(f2b(acc[i][j][2])); pk.w = b2u(f2b(acc[i][j][3]));
          *(ushort4*)(P2 + ((bb*16 + h)*128 + d - 128)*2048 + s) = pk;
        }
      }
    } else { // OUT_MODE == 3: q RoPE + scale -> Qt (B,H,S,192)
      bool rope = ((n0w % 192) == 128);
#pragma unroll
      for (int r = 0; r < 4; r++) {
        long row = tok + r;
#pragma unroll
        for (int j = 0; j < 4; j++) {
          long col = n0w + j*16 + lr;
          float x = acc[i][j][r], val;
          if (rope) {
            int id = j*16 + lr;
            float partner = acc[i][j^2][r];
            float rot = (j < 2) ? -partner : partner;
            val = x*cosb[row*64 + id] + rot*sinb[row*64 + id];
          } else {
            val = x;
          }
          long h = col / 192, d = col % 192;
          P1[((bb*16 + h)*2048 + s + r)*192 + d] = f2b(val * SCALE_L2E);
        }
      }
    }
  }
}

__global__ __launch_bounds__(512) void gemm0_k(const BF16* __restrict__ A, const BF16* __restrict__ B,
                                               float* __restrict__ C, int M, int N, int K) {
  __shared__ __align__(16) BF16 As[2*256*64];   // 64 KB
  __shared__ __align__(16) BF16 Bs[2*128*64];   // 32 KB
  gemm_body<0>(A, B, C, M, N, K, nullptr, nullptr, nullptr, nullptr,
               blockIdx.x, blockIdx.y, As, Bs);
}

// q_b (384 blocks, mode 3) + kv_b (512 blocks, mode 2) in one launch: tails overlap.
__global__ __launch_bounds__(512) void gemm_qkv_k(const BF16* __restrict__ qan, const BF16* __restrict__ Wqb,
                                                  const BF16* __restrict__ kvn, const BF16* __restrict__ Wkvb,
                                                  const float* __restrict__ cosb, const float* __restrict__ sinb,
                                                  BF16* __restrict__ Qt, BF16* __restrict__ Kt,
                                                  BF16* __restrict__ Vt) {
  __shared__ __align__(16) BF16 As[2*256*64];
  __shared__ __align__(16) BF16 Bs[2*128*64];
  int bid = blockIdx.x;
  if (bid < 384) {
    gemm_body<3>(qan, Wqb, nullptr, 4096, 3072, 1536, cosb, sinb, Qt, nullptr,
                 bid % 24, bid / 24, As, Bs);
  } else {
    bid -= 384;
    gemm_body<2>(kvn, Wkvb, nullptr, 4096, 4096, 512, nullptr, nullptr, Kt, Vt,
                 bid % 32, bid / 32, As, Bs);
  }
}

// ---------------------------------------------------------------- fused: rmsnorm(1536) + rmsnorm(512) + k_rot RoPE
// One block per token row of qakv (stride 2112: [q_a 1536 | ckv 512 | krot 64]).
__global__ __launch_bounds__(256) void norms_k(const float* __restrict__ qakv,
                                               const float* __restrict__ qw, const float* __restrict__ kw,
                                               const float* __restrict__ cosb, const float* __restrict__ sinb,
                                               BF16* __restrict__ qan, BF16* __restrict__ kvn,
                                               BF16* __restrict__ Kt) {
  long row = blockIdx.x;
  const float* xr = qakv + row * 2112;
  int tid = threadIdx.x;
  __shared__ float red[4];
  // ---- rmsnorm D=1536 -> qan
  {
    float ss = 0.f;
    for (int i = tid*4; i < 1536; i += 1024) {
      float4 v = *(const float4*)(xr + i);
      ss += v.x*v.x + v.y*v.y + v.z*v.z + v.w*v.w;
    }
#pragma unroll
    for (int off = 32; off > 0; off >>= 1) ss += __shfl_down(ss, off);
    if ((tid & 63) == 0) red[tid >> 6] = ss;
    __syncthreads();
    float rs = rsqrtf((red[0]+red[1]+red[2]+red[3]) / 1536.f + 1e-6f);
    BF16* yr = qan + row * 1536;
    for (int i = tid*4; i < 1536; i += 1024) {
      float4 v = *(const float4*)(xr + i);
      yr[i+0] = f2b(v.x * qw[i+0] * rs);
      yr[i+1] = f2b(v.y * qw[i+1] * rs);
      yr[i+2] = f2b(v.z * qw[i+2] * rs);
      yr[i+3] = f2b(v.w * qw[i+3] * rs);
    }
  }
  __syncthreads();
  // ---- rmsnorm D=512 (offset 1536) -> kvn
  {
    float ss = 0.f;
    for (int i = tid*4; i < 512; i += 1024) {
      float4 v = *(const float4*)(xr + 1536 + i);
      ss += v.x*v.x + v.y*v.y + v.z*v.z + v.w*v.w;
    }
#pragma unroll
    for (int off = 32; off > 0; off >>= 1) ss += __shfl_down(ss, off);
    if ((tid & 63) == 0) red[tid >> 6] = ss;
    __syncthreads();
    float rs = rsqrtf((red[0]+red[1]+red[2]+red[3]) / 512.f + 1e-6f);
    BF16* yr = kvn + row * 512;
    for (int i = tid*4; i < 512; i += 1024) {
      float4 v = *(const float4*)(xr + 1536 + i);
      yr[i+0] = f2b(v.x * kw[i+0] * rs);
      yr[i+1] = f2b(v.y * kw[i+1] * rs);
      yr[i+2] = f2b(v.z * kw[i+2] * rs);
      yr[i+3] = f2b(v.w * kw[i+3] * rs);
    }
  }
  // ---- k_rot RoPE -> Kt[...,128:192] broadcast to all 16 heads
  if (tid < 64) {
    int i = tid;
    const float* kr = xr + 2048;
    float x = kr[i];
    float rot = (i < 32) ? -kr[i + 32] : kr[i - 32];
    BF16 v = f2b(x * cosb[row*64 + i] + rot * sinb[row*64 + i]);
    long b = row >> 11, s = row & 2047;
    long base = ((b*16)*2048 + s)*192 + 128 + i;
#pragma unroll
    for (int h = 0; h < 16; h++) Kt[base + (long)h*2048*192] = v;
  }
}

// ---------------------------------------------------------------- causal flash attention
// grid 512, 512 threads (8 waves), one 128-row q-tile per block.
// Rounds 3/6/7 falsified the TLP and barrier theories (1 block/CU regardless of
// LDS; 1-barrier dbuf = 2-barrier). Arithmetic says the LDS READ pipe is the
// floor: previously every wave read the FULL K+V tile (8x redundancy, ~400KB
// per block per k-tile ~ 3140 cyc at 128B/clk). This version splits waves over
// (q-group, k-half): wave w -> qg=w>>1 owns 32 q-rows, kh=w&1 owns a 32-kpos
// half of each 64-kpos k-tile. Each wave reads HALF of K (12 b128) and V
// (8 b128), each fragment feeds 2 MFMA (two 16-row q-frags) -> K/V LDS read
// traffic x0.5, same MFMA count, same staging. The two k-half waves keep
// independent online-softmax state (m,l,O) -- no per-tile cross-wave sync --
// merged once per block in the epilogue (split-K flash combine, f=exp2(m_h-m*);
// m of half 0 is always finite since every row >= its first kpos, and
// exp2(-inf)=0 kills empty halves). Merge scratch aliases the dead K/V LDS.
// Q prescaled by 192^-0.5*log2e; V is (B,H,128,S) transposed. Softmax: DPP
// 16-lane all-reduce + defer-max (T13, THR=8 exp2-domain). Staging: depth-1
// register prefetch, STATIC register arrays (r9: dynamic idx -> scratch, 13x).
#define LK 200
#define LV 72
#define LPW 40
__global__ __launch_bounds__(512) void flash_k(const BF16* __restrict__ Qt, const BF16* __restrict__ Kt,
                                               const BF16* __restrict__ Vt, BF16* __restrict__ O) {
  // [Ks 2x64xLK | Vs 2x128xLV | Ps 8x32xLPW] = 51200 + 36864 + 20480 = 108544 B
  __shared__ __align__(16) char smem[108544];
  BF16* KsB = (BF16*)smem;
  BF16* VsB = (BF16*)(smem + 51200);
  BF16* PsB = (BF16*)(smem + 88064);
  float* Om = (float*)smem;            // epilogue merge: [128][128] f32 (aliases Ks/Vs)
  float* Ml = (float*)(smem + 65536);  // epilogue merge: [128][2] f32 {m,l}

  int tid = threadIdx.x, wave = tid >> 6, lane = tid & 63;
  int lr = lane & 15, quad = lane >> 4;
  int qg = wave >> 1, kh = wave & 1;
  int F = blockIdx.x;
  int g = F & 31, u = F >> 5;
  int qt = (u < 8) ? u : 23 - u;      // co-dispatch pairing: qt + (15-qt)
  int h = g & 15, b = g >> 4;
  const BF16* Qb = Qt + ((long)(b*16 + h) * 2048) * 192;
  const BF16* Kb = Kt + ((long)(b*16 + h) * 2048) * 192;
  const BF16* Vb = Vt + ((long)(b*16 + h) * 128) * 2048;
  const float NEG_INF = -__builtin_inff();

  // staging geometry: K 1536 chunks / 512 thr = 3; V 1024 chunks / 512 thr = 2
  int krow[3], kcol[3];
#pragma unroll
  for (int i = 0; i < 3; i++) {
    int c = tid + 512*i;
    krow[i] = c / 24; kcol[i] = (c % 24) * 8;
  }
  int vrow[2], vcol[2];
#pragma unroll
  for (int i = 0; i < 2; i++) {
    int c = tid + 512*i;
    vrow[i] = c >> 3; vcol[i] = (c & 7) * 8;
  }

  bf16x8 kreg[3], vreg[2];   // depth-1, statically indexed
  auto stage_load = [&](int k0) {
#pragma unroll
    for (int i = 0; i < 3; i++)
      kreg[i] = *(const bf16x8*)(Kb + (long)(k0 + krow[i])*192 + kcol[i]);
#pragma unroll
    for (int i = 0; i < 2; i++)
      vreg[i] = *(const bf16x8*)(Vb + (long)vrow[i]*2048 + k0 + vcol[i]);
  };
  auto stage_store = [&](int s) {
    BF16* Kd = KsB + s*(64*LK);
    BF16* Vd = VsB + s*(128*LV);
#pragma unroll
    for (int i = 0; i < 3; i++)
      *(bf16x8*)(Kd + krow[i]*LK + kcol[i]) = kreg[i];
#pragma unroll
    for (int i = 0; i < 2; i++)
      *(bf16x8*)(Vd + vrow[i]*LV + vcol[i]) = vreg[i];
  };

  int wq0 = qt*128 + qg*32;          // this wave's first q-row (32 rows)
  bf16x8 qf[2][6];
#pragma unroll
  for (int s = 0; s < 2; s++) {
    const BF16* qp = Qb + (long)(wq0 + s*16 + lr) * 192 + quad*8;
#pragma unroll
    for (int f = 0; f < 6; f++) qf[s][f] = *(const bf16x8*)(qp + f*32);
  }
  float m_i[2][4], l_i[2][4];
#pragma unroll
  for (int s = 0; s < 2; s++)
#pragma unroll
    for (int r = 0; r < 4; r++) { m_i[s][r] = NEG_INF; l_i[s][r] = 0.f; }
  floatx4 o_acc[2][8] = {};
  BF16* Psw = PsB + wave*(32*LPW);

  int nk = 2*qt + 2;
  stage_load(0);
  stage_store(0);
  __syncthreads();
  int cur = 0;
  for (int kt = 0; kt < nk; kt++) {
    if (kt + 1 < nk) stage_load((kt + 1) * 64);  // issue early; lands during compute
    int kbase = kt*64 + kh*32;                   // this wave's 32-kpos window
    if (kbase <= wq0 + 31) {                     // wave has unmasked columns
      const BF16* Kc = KsB + cur*(64*LK);
      const BF16* Vc = VsB + cur*(128*LV);
      floatx4 st[2][2] = {};
      __builtin_amdgcn_s_setprio(1);
#pragma unroll
      for (int t = 0; t < 2; t++)
#pragma unroll
        for (int f = 0; f < 6; f++) {
          bf16x8 kf = *(const bf16x8*)(Kc + (kh*32 + t*16 + lr)*LK + f*32 + quad*8);
          st[0][t] = __builtin_amdgcn_mfma_f32_16x16x32_bf16(qf[0][f], kf, st[0][t], 0, 0, 0);
          st[1][t] = __builtin_amdgcn_mfma_f32_16x16x32_bf16(qf[1][f], kf, st[1][t], 0, 0, 0);
        }
      __builtin_amdgcn_s_setprio(0);
      float mt[2][4];
#pragma unroll
      for (int s = 0; s < 2; s++)
#pragma unroll
        for (int r = 0; r < 4; r++) mt[s][r] = NEG_INF;
      if (kbase + 31 > wq0) { // window crosses the diagonal: causal mask
#pragma unroll
        for (int s = 0; s < 2; s++) {
          int rbase = wq0 + s*16 + quad*4 - kbase;   // row - kbase
#pragma unroll
          for (int t = 0; t < 2; t++) {
            int coff = t*16 + lr;
#pragma unroll
            for (int r = 0; r < 4; r++) {
              float sc = st[s][t][r];
              if (coff > rbase + r) sc = NEG_INF;
              st[s][t][r] = sc;
              mt[s][r] = fmaxf(mt[s][r], sc);
            }
          }
        }
      } else {
#pragma unroll
        for (int s = 0; s < 2; s++)
#pragma unroll
          for (int t = 0; t < 2; t++)
#pragma unroll
            for (int r = 0; r < 4; r++) mt[s][r] = fmaxf(mt[s][r], st[s][t][r]);
      }
#pragma unroll
      for (int s = 0; s < 2; s++)
#pragma unroll
        for (int r = 0; r < 4; r++) mt[s][r] = row_allmax(mt[s][r]);
      // defer-max (T13): skip O/l rescale when wave-wide max growth <= 8
      float gr = NEG_INF;
#pragma unroll
      for (int s = 0; s < 2; s++)
#pragma unroll
        for (int r = 0; r < 4; r++) gr = fmaxf(gr, mt[s][r] - m_i[s][r]);
      gr = fmaxf(gr, __shfl_xor(gr, 16));
      gr = fmaxf(gr, __shfl_xor(gr, 32));
      if (gr > 8.f) {
#pragma unroll
        for (int s = 0; s < 2; s++)
#pragma unroll
          for (int r = 0; r < 4; r++) {
            float mn = fmaxf(m_i[s][r], mt[s][r]);
            float alpha = fast_exp2(m_i[s][r] - mn);
            m_i[s][r] = mn;
            l_i[s][r] *= alpha;
#pragma unroll
            for (int v = 0; v < 8; v++) o_acc[s][v][r] *= alpha;
          }
      }
      float rsum[2][4];
#pragma unroll
      for (int s = 0; s < 2; s++)
#pragma unroll
        for (int r = 0; r < 4; r++) rsum[s][r] = 0.f;
#pragma unroll
      for (int s = 0; s < 2; s++)
#pragma unroll
        for (int t = 0; t < 2; t++)
#pragma unroll
          for (int r = 0; r < 4; r++) {
            float p = fast_exp2(st[s][t][r] - m_i[s][r]);
            st[s][t][r] = p;
            rsum[s][r] += p;
          }
#pragma unroll
      for (int s = 0; s < 2; s++)
#pragma unroll
        for (int r = 0; r < 4; r++) { rsum[s][r] = row_allsum(rsum[s][r]); l_i[s][r] += rsum[s][r]; }
      // P (C-layout) -> wave-private LDS -> A-layout (same-wave DS ordering)
#pragma unroll
      for (int s = 0; s < 2; s++)
#pragma unroll
        for (int t = 0; t < 2; t++)
#pragma unroll
          for (int r = 0; r < 4; r++)
            Psw[(s*16 + quad*4 + r)*LPW + t*16 + lr] = f2b(st[s][t][r]);
      bf16x8 pa0 = *(const bf16x8*)(Psw + lr*LPW + quad*8);
      bf16x8 pa1 = *(const bf16x8*)(Psw + (16 + lr)*LPW + quad*8);
      __builtin_amdgcn_s_setprio(1);
#pragma unroll
      for (int v = 0; v < 8; v++) {
        bf16x8 vf = *(const bf16x8*)(Vc + (v*16+lr)*LV + kh*32 + quad*8);
        o_acc[0][v] = __builtin_amdgcn_mfma_f32_16x16x32_bf16(pa0, vf, o_acc[0][v], 0, 0, 0);
        o_acc[1][v] = __builtin_amdgcn_mfma_f32_16x16x32_bf16(pa1, vf, o_acc[1][v], 0, 0, 0);
      }
      __builtin_amdgcn_s_setprio(0);
    }
    // store tile kt+1 into the other buffer; publish via barrier
    if (kt + 1 < nk) stage_store(cur ^ 1);
    __syncthreads();
    cur ^= 1;
  }

  // ---- epilogue: merge the two k-halves (split-K flash combine), then write.
  // k-loop's final barrier passed -> Ks/Vs dead, alias as f32 scratch.
  if (kh == 1) {
#pragma unroll
    for (int s = 0; s < 2; s++)
#pragma unroll
      for (int v = 0; v < 8; v++)
#pragma unroll
        for (int r = 0; r < 4; r++)
          Om[(qg*32 + s*16 + quad*4 + r)*128 + v*16 + lr] = o_acc[s][v][r];
    if (lr == 0) {
#pragma unroll
      for (int s = 0; s < 2; s++)
#pragma unroll
        for (int r = 0; r < 4; r++) {
          int row32 = qg*32 + s*16 + quad*4 + r;
          Ml[row32*2]     = m_i[s][r];
          Ml[row32*2 + 1] = l_i[s][r];
        }
    }
  }
  __syncthreads();
  if (kh == 0) {
#pragma unroll
    for (int s = 0; s < 2; s++)
#pragma unroll
      for (int r = 0; r < 4; r++) {
        int row32 = qg*32 + s*16 + quad*4 + r;
        float m1 = Ml[row32*2], l1 = Ml[row32*2 + 1];
        float m0 = m_i[s][r],  l0 = l_i[s][r];
        float ms = fmaxf(m0, m1);                  // m0 always finite (kpos 0 valid)
        float f0 = fast_exp2(m0 - ms);
        float f1 = fast_exp2(m1 - ms);             // exp2(-inf)=0 for empty half
        float linv = 1.f / (l0*f0 + l1*f1);
        long rowg = qt*128 + row32;
#pragma unroll
        for (int v = 0; v < 8; v++) {
          float o1 = Om[row32*128 + v*16 + lr];
          O[((long)b*2048 + rowg)*2048 + h*128 + v*16 + lr] =
              f2b((o_acc[s][v][r]*f0 + o1*f1) * linv);
        }
      }
  }
}

// ---------------------------------------------------------------- launch
extern "C" void kernel_launch(void* const* d_in, const int* in_sizes, int n_in,
                              void* d_out, int out_size, void* d_ws, size_t ws_size,
                              hipStream_t stream) {
  const float* hidden      = (const float*)d_in[0];
  const float* cosb        = (const float*)d_in[1];
  const float* sinb        = (const float*)d_in[2];
  const float* q_a_W       = (const float*)d_in[3];
  const float* q_a_norm_w  = (const float*)d_in[4];
  const float* q_b_W       = (const float*)d_in[5];
  const float* kv_a_W      = (const float*)d_in[6];
  const float* kv_a_norm_w = (const float*)d_in[7];
  const float* kv_b_W      = (const float*)d_in[8];
  const float* o_W         = (const float*)d_in[9];
  float* out = (float*)d_out;

  const int Mrows = 4096;

  char* ws = (char*)d_ws; size_t off = 0;
  auto alloc = [&](size_t bytes) -> void* {
    void* p = ws + off; off = (off + bytes + 255) & ~(size_t)255; return p;
  };
  BF16* hb    = (BF16*)alloc((size_t)4096*2048*2);
  BF16* Wqakv = (BF16*)alloc((size_t)2112*2048*2);   // rows 0..1536 = q_a_W, 1536..2112 = kv_a_W
  BF16* Wqb   = (BF16*)alloc((size_t)3072*1536*2);
  BF16* Wkvb  = (BF16*)alloc((size_t)4096*512*2);
  BF16* Wo    = (BF16*)alloc((size_t)2048*2048*2);
  float* qakv = (float*)alloc((size_t)4096*2112*4);  // cols 0..1536 = q_a out, 1536..2112 = ckv
  BF16* qan   = (BF16*)alloc((size_t)4096*1536*2);
  BF16* kvn   = (BF16*)alloc((size_t)4096*512*2);
  BF16* Qt    = (BF16*)alloc((size_t)2*16*2048*192*2);
  BF16* Kt    = (BF16*)alloc((size_t)2*16*2048*192*2);
  BF16* Vt    = (BF16*)alloc((size_t)2*16*128*2048*2); // transposed (B,H,128,S)
  BF16* attn  = (BF16*)alloc((size_t)4096*2048*2);

  CastArgs ca;
  ca.src[0] = hidden;  ca.dst[0] = hb;                 ca.n[0] = (long)4096*2048;
  ca.src[1] = q_a_W;   ca.dst[1] = Wqakv;              ca.n[1] = (long)1536*2048;
  ca.src[2] = kv_a_W;  ca.dst[2] = Wqakv + (long)1536*2048; ca.n[2] = (long)576*2048;
  ca.src[3] = q_b_W;   ca.dst[3] = Wqb;                ca.n[3] = (long)3072*1536;
  ca.src[4] = kv_b_W;  ca.dst[4] = Wkvb;               ca.n[4] = (long)4096*512;
  ca.src[5] = o_W;     ca.dst[5] = Wo;                 ca.n[5] = (long)2048*2048;
  cast_multi_k<<<dim3(1024, 6), dim3(256), 0, stream>>>(ca);

  // [q_a | ckv] = hidden @ [q_a_W | kv_a_W].T  (4096 x 2112, K=2048), fp32
  gemm0_k<<<dim3(17, 16), dim3(512), 0, stream>>>(hb, Wqakv, qakv, Mrows, 2112, 2048);

  // fused rmsnorms + k_rot RoPE
  norms_k<<<dim3(4096), dim3(256), 0, stream>>>(qakv, q_a_norm_w, kv_a_norm_w,
                                                cosb, sinb, qan, kvn, Kt);

  // q_b (RoPE+scale -> Qt) and kv_b (scatter -> Kt / Vt^T) in one launch
  gemm_qkv_k<<<dim3(896), dim3(512), 0, stream>>>(qan, Wqb, kvn, Wkvb, cosb, sinb, Qt, Kt, Vt);

  flash_k<<<dim3(512), dim3(512), 0, stream>>>(Qt, Kt, Vt, attn);

  // out = attn @ o_W.T (4096x2048, K=2048), fp32 -> d_out
  gemm0_k<<<dim3(16, 16), dim3(512), 0, stream>>>(attn, Wo, out, Mrows, 2048, 2048);
}

// Round 10
// 450.334 us; speedup vs baseline: 1.0149x; 1.0149x over previous
//
#include <hip/hip_runtime.h>
#include <hip/hip_bf16.h>

// DeepSeek V3 MLA attention forward, MI355X (gfx950).
// B=2, S=2048, D=2048, H=16, NOPE=128, ROPE=64, VDIM=128, QKD=192.

typedef __bf16 bf16x8 __attribute__((ext_vector_type(8)));
typedef float floatx4 __attribute__((ext_vector_type(4)));
#define BF16 __hip_bfloat16

static __device__ __forceinline__ BF16 f2b(float x) { return __float2bfloat16(x); }
static __device__ __forceinline__ unsigned short b2u(BF16 x) { return *(unsigned short*)&x; }
static __device__ __forceinline__ float fast_exp2(float x) { return __builtin_amdgcn_exp2f(x); }

// DPP cross-lane move within a 16-lane row (VALU pipe, ~8 cyc vs ~60+ for ds_swizzle).
template<int CTRL>
static __device__ __forceinline__ float dpp_mov(float x) {
  int xi = __builtin_bit_cast(int, x);
  int yi = __builtin_amdgcn_update_dpp(xi, xi, CTRL, 0xF, 0xF, false);
  return __builtin_bit_cast(float, yi);
}
// all-reduce across the 16 lanes of a DPP row: quad xor1, quad xor2, half-mirror, mirror
static __device__ __forceinline__ float row_allmax(float x) {
  x = fmaxf(x, dpp_mov<0xB1>(x));   // quad_perm [1,0,3,2]
  x = fmaxf(x, dpp_mov<0x4E>(x));   // quad_perm [2,3,0,1]
  x = fmaxf(x, dpp_mov<0x141>(x));  // row_half_mirror
  x = fmaxf(x, dpp_mov<0x140>(x));  // row_mirror
  return x;
}
static __device__ __forceinline__ float row_allsum(float x) {
  x += dpp_mov<0xB1>(x);
  x += dpp_mov<0x4E>(x);
  x += dpp_mov<0x141>(x);
  x += dpp_mov<0x140>(x);
  return x;
}

static __device__ __forceinline__ void load_lds16(const BF16* g, BF16* l) {
  __builtin_amdgcn_global_load_lds((__attribute__((address_space(1))) void*)(void*)g,
                                   (__attribute__((address_space(3))) void*)(void*)l,
                                   16, 0, 0);
}

// ---------------------------------------------------------------- multi-region cast f32->bf16
struct CastArgs {
  const float* src[6];
  BF16* dst[6];
  long n[6];
};
__global__ void cast_multi_k(CastArgs a) {
  int r = blockIdx.y;
  long n = a.n[r];
  const float* __restrict__ x = a.src[r];
  BF16* __restrict__ y = a.dst[r];
  for (long i = ((long)blockIdx.x * 256 + threadIdx.x) * 4; i + 3 < n;
       i += (long)gridDim.x * 1024) {
    float4 v = *(const float4*)(x + i);
    y[i+0] = f2b(v.x); y[i+1] = f2b(v.y); y[i+2] = f2b(v.z); y[i+3] = f2b(v.w);
  }
}

// ---------------------------------------------------------------- NT GEMM v2
// C[M][N] = A[M][K]*B[N][K]^T.  256x128 tile, BK=64, 512 thr = 8 waves (4x2),
// per-wave 64x64 output (acc[4][4]).  Double-buffered LDS (96 KB),
// global_load_lds staging with XOR-swizzled source (T2), raw s_barrier +
// counted s_waitcnt vmcnt(6) pipeline (T4), s_setprio around MFMA (T5).
// OUT_MODE: 0 = fp32 C;  2 = kv scatter -> Kt (scalar) / Vt transposed (8B packed);
//           3 = q RoPE+scale scatter -> Qt (scale includes log2(e) for exp2 softmax).
template<int OUT_MODE>
static __device__ __forceinline__ void gemm_body(
    const BF16* __restrict__ A, const BF16* __restrict__ B, void* __restrict__ C,
    int M, int N, int K, const float* __restrict__ cosb, const float* __restrict__ sinb,
    BF16* __restrict__ P1, BF16* __restrict__ P2, int bx, int by, BF16* As, BF16* Bs) {
  int tid = threadIdx.x, wave = tid >> 6, lane = tid & 63;
  int wr = wave >> 1, wc = wave & 1, lr = lane & 15, quad = lane >> 4;
  long m0 = (long)by * 256, n0 = (long)bx * 128;

  // --- staging descriptors: per thread per K-tile, A = 4 chunks, B = 2 chunks (16B each).
  // chunk c -> tile row r = c>>3, chunk col k = c&7. LDS linear (r,k) receives
  // global chunk (r, k ^ (r&7)) so swizzled reads recover logical columns.
  long asrc[4]; int adst[4];
#pragma unroll
  for (int i = 0; i < 4; i++) {
    int c = wave*64 + lane + 512*i;
    int r = c >> 3, k = c & 7;
    asrc[i] = (m0 + r) * (long)K + ((k ^ (r & 7)) << 3);
    adst[i] = wave*512 + i*4096;          // wave-uniform LDS base (HW adds lane*16B)
  }
  long bsrc[2]; int bdst[2];
#pragma unroll
  for (int i = 0; i < 2; i++) {
    int c = wave*64 + lane + 512*i;
    int r = c >> 3, k = c & 7;
    long bn = n0 + r; if (bn >= N) bn = N - 1;  // N-tail clamp (stores are guarded)
    bsrc[i] = bn * (long)K + ((k ^ (r & 7)) << 3);
    bdst[i] = wave*512 + i*4096;
  }

  auto stage = [&](int bi, int kt) {   // 6 global_load_lds per wave per call
    long k0 = (long)kt << 6;
    BF16* Ad = As + bi*16384;
    BF16* Bd = Bs + bi*8192;
#pragma unroll
    for (int i = 0; i < 4; i++) load_lds16(A + asrc[i] + k0, Ad + adst[i]);
#pragma unroll
    for (int i = 0; i < 2; i++) load_lds16(B + bsrc[i] + k0, Bd + bdst[i]);
  };

  // --- read offsets (row*64 elems; chunk col XORed with row&7 = lr&7)
  int aoff[4], boff[4];
#pragma unroll
  for (int i = 0; i < 4; i++) aoff[i] = (wr*64 + i*16 + lr) * 64;
#pragma unroll
  for (int j = 0; j < 4; j++) boff[j] = (wc*64 + j*16 + lr) * 64;
  int x0 = ((quad    ) ^ (lr & 7)) << 3;   // kk=0: chunks 0..3
  int x1 = ((quad ^ 4) ^ (lr & 7)) << 3;   // kk=1: chunks 4..7

  floatx4 acc[4][4] = {};
  int NT = K >> 6;

  // prologue: stage tiles 0 and 1, wait only tile 0 (12 in flight -> 6)
  stage(0, 0);
  stage(1, 1);
  asm volatile("s_waitcnt vmcnt(6)" ::: "memory");
  __builtin_amdgcn_s_barrier();

  int cur = 0;
  for (int t = 0; t < NT; t++) {
    const BF16* Ab = As + cur*16384;
    const BF16* Bb = Bs + cur*8192;
    bf16x8 a0[4], a1[4], b0[4], b1[4];
#pragma unroll
    for (int i = 0; i < 4; i++) {
      a0[i] = *(const bf16x8*)(Ab + aoff[i] + x0);
      a1[i] = *(const bf16x8*)(Ab + aoff[i] + x1);
    }
#pragma unroll
    for (int j = 0; j < 4; j++) {
      b0[j] = *(const bf16x8*)(Bb + boff[j] + x0);
      b1[j] = *(const bf16x8*)(Bb + boff[j] + x1);
    }
    // all fragments in regs -> buf[cur] is free for restaging after this barrier
    asm volatile("s_waitcnt lgkmcnt(0)" ::: "memory");
    __builtin_amdgcn_s_barrier();
    if (t + 2 < NT) stage(cur, t + 2);   // issue-early: latency hides under MFMA
    __builtin_amdgcn_s_setprio(1);
#pragma unroll
    for (int i = 0; i < 4; i++)
#pragma unroll
      for (int j = 0; j < 4; j++)
        acc[i][j] = __builtin_amdgcn_mfma_f32_16x16x32_bf16(a0[i], b0[j], acc[i][j], 0, 0, 0);
#pragma unroll
    for (int i = 0; i < 4; i++)
#pragma unroll
      for (int j = 0; j < 4; j++)
        acc[i][j] = __builtin_amdgcn_mfma_f32_16x16x32_bf16(a1[i], b1[j], acc[i][j], 0, 0, 0);
    __builtin_amdgcn_s_setprio(0);
    // retire tile t+1's 6 loads (t+2's 6 stay in flight); publish via barrier
    if (t + 2 < NT)      { asm volatile("s_waitcnt vmcnt(6)" ::: "memory"); }
    else if (t + 1 < NT) { asm volatile("s_waitcnt vmcnt(0)" ::: "memory"); }
    __builtin_amdgcn_s_barrier();
    __builtin_amdgcn_sched_barrier(0);
    cur ^= 1;
  }

  long n0w = n0 + wc*64;
  // 192^-0.5 * log2(e): softmax runs in exp2 domain.
  const float SCALE_L2E = 0.104117546f;
#pragma unroll
  for (int i = 0; i < 4; i++) {
    long tok = m0 + wr*64 + i*16 + quad*4;   // 4 consecutive tokens (r=0..3)
    long bb = tok >> 11, s = tok & 2047;
    if (OUT_MODE == 0) {
#pragma unroll
      for (int r = 0; r < 4; r++) {
        long row = tok + r;
#pragma unroll
        for (int j = 0; j < 4; j++) {
          long col = n0w + j*16 + lr;
          if (col < N) ((float*)C)[row*(long)N + col] = acc[i][j][r];
        }
      }
    } else if (OUT_MODE == 2) {
#pragma unroll
      for (int j = 0; j < 4; j++) {
        long col = n0w + j*16 + lr;
        long h = col >> 8, d = col & 255;
        if (d < 128) {
#pragma unroll
          for (int r = 0; r < 4; r++)
            P1[((bb*16 + h)*2048 + s + r)*192 + d] = f2b(acc[i][j][r]);
        } else {
          // Vt transposed (B,H,128,2048): 4 consecutive tokens packed, 8B store
          ushort4 pk;
          pk.x = b2u(f2b(acc[i][j][0])); pk.y = b2u(f2b(acc[i][j][1]));
          pk.z = b2u(f2b(acc[i][j][2])); pk.w = b2u(f2b(acc[i][j][3]));
          *(ushort4*)(P2 + ((bb*16 + h)*128 + d - 128)*2048 + s) = pk;
        }
      }
    } else { // OUT_MODE == 3: q RoPE + scale -> Qt (B,H,S,192)
      bool rope = ((n0w % 192) == 128);
#pragma unroll
      for (int r = 0; r < 4; r++) {
        long row = tok + r;
#pragma unroll
        for (int j = 0; j < 4; j++) {
          long col = n0w + j*16 + lr;
          float x = acc[i][j][r], val;
          if (rope) {
            int id = j*16 + lr;
            float partner = acc[i][j^2][r];
            float rot = (j < 2) ? -partner : partner;
            val = x*cosb[row*64 + id] + rot*sinb[row*64 + id];
          } else {
            val = x;
          }
          long h = col / 192, d = col % 192;
          P1[((bb*16 + h)*2048 + s + r)*192 + d] = f2b(val * SCALE_L2E);
        }
      }
    }
  }
}

__global__ __launch_bounds__(512) void gemm0_k(const BF16* __restrict__ A, const BF16* __restrict__ B,
                                               float* __restrict__ C, int M, int N, int K) {
  __shared__ __align__(16) BF16 As[2*256*64];   // 64 KB
  __shared__ __align__(16) BF16 Bs[2*128*64];   // 32 KB
  gemm_body<0>(A, B, C, M, N, K, nullptr, nullptr, nullptr, nullptr,
               blockIdx.x, blockIdx.y, As, Bs);
}

// q_b (384 blocks, mode 3) + kv_b (512 blocks, mode 2) in one launch: tails overlap.
__global__ __launch_bounds__(512) void gemm_qkv_k(const BF16* __restrict__ qan, const BF16* __restrict__ Wqb,
                                                  const BF16* __restrict__ kvn, const BF16* __restrict__ Wkvb,
                                                  const float* __restrict__ cosb, const float* __restrict__ sinb,
                                                  BF16* __restrict__ Qt, BF16* __restrict__ Kt,
                                                  BF16* __restrict__ Vt) {
  __shared__ __align__(16) BF16 As[2*256*64];
  __shared__ __align__(16) BF16 Bs[2*128*64];
  int bid = blockIdx.x;
  if (bid < 384) {
    gemm_body<3>(qan, Wqb, nullptr, 4096, 3072, 1536, cosb, sinb, Qt, nullptr,
                 bid % 24, bid / 24, As, Bs);
  } else {
    bid -= 384;
    gemm_body<2>(kvn, Wkvb, nullptr, 4096, 4096, 512, nullptr, nullptr, Kt, Vt,
                 bid % 32, bid / 32, As, Bs);
  }
}

// ---------------------------------------------------------------- fused: rmsnorm(1536) + rmsnorm(512) + k_rot RoPE
// One block per token row of qakv (stride 2112: [q_a 1536 | ckv 512 | krot 64]).
__global__ __launch_bounds__(256) void norms_k(const float* __restrict__ qakv,
                                               const float* __restrict__ qw, const float* __restrict__ kw,
                                               const float* __restrict__ cosb, const float* __restrict__ sinb,
                                               BF16* __restrict__ qan, BF16* __restrict__ kvn,
                                               BF16* __restrict__ Kt) {
  long row = blockIdx.x;
  const float* xr = qakv + row * 2112;
  int tid = threadIdx.x;
  __shared__ float red[4];
  // ---- rmsnorm D=1536 -> qan
  {
    float ss = 0.f;
    for (int i = tid*4; i < 1536; i += 1024) {
      float4 v = *(const float4*)(xr + i);
      ss += v.x*v.x + v.y*v.y + v.z*v.z + v.w*v.w;
    }
#pragma unroll
    for (int off = 32; off > 0; off >>= 1) ss += __shfl_down(ss, off);
    if ((tid & 63) == 0) red[tid >> 6] = ss;
    __syncthreads();
    float rs = rsqrtf((red[0]+red[1]+red[2]+red[3]) / 1536.f + 1e-6f);
    BF16* yr = qan + row * 1536;
    for (int i = tid*4; i < 1536; i += 1024) {
      float4 v = *(const float4*)(xr + i);
      yr[i+0] = f2b(v.x * qw[i+0] * rs);
      yr[i+1] = f2b(v.y * qw[i+1] * rs);
      yr[i+2] = f2b(v.z * qw[i+2] * rs);
      yr[i+3] = f2b(v.w * qw[i+3] * rs);
    }
  }
  __syncthreads();
  // ---- rmsnorm D=512 (offset 1536) -> kvn
  {
    float ss = 0.f;
    for (int i = tid*4; i < 512; i += 1024) {
      float4 v = *(const float4*)(xr + 1536 + i);
      ss += v.x*v.x + v.y*v.y + v.z*v.z + v.w*v.w;
    }
#pragma unroll
    for (int off = 32; off > 0; off >>= 1) ss += __shfl_down(ss, off);
    if ((tid & 63) == 0) red[tid >> 6] = ss;
    __syncthreads();
    float rs = rsqrtf((red[0]+red[1]+red[2]+red[3]) / 512.f + 1e-6f);
    BF16* yr = kvn + row * 512;
    for (int i = tid*4; i < 512; i += 1024) {
      float4 v = *(const float4*)(xr + 1536 + i);
      yr[i+0] = f2b(v.x * kw[i+0] * rs);
      yr[i+1] = f2b(v.y * kw[i+1] * rs);
      yr[i+2] = f2b(v.z * kw[i+2] * rs);
      yr[i+3] = f2b(v.w * kw[i+3] * rs);
    }
  }
  // ---- k_rot RoPE -> Kt[...,128:192] broadcast to all 16 heads
  if (tid < 64) {
    int i = tid;
    const float* kr = xr + 2048;
    float x = kr[i];
    float rot = (i < 32) ? -kr[i + 32] : kr[i - 32];
    BF16 v = f2b(x * cosb[row*64 + i] + rot * sinb[row*64 + i]);
    long b = row >> 11, s = row & 2047;
    long base = ((b*16)*2048 + s)*192 + 128 + i;
#pragma unroll
    for (int h = 0; h < 16; h++) Kt[base + (long)h*2048*192] = v;
  }
}

// ---------------------------------------------------------------- causal flash attention
// grid 512, 512 threads (8 waves). One q-tile (128 rows) per block — the
// best-measured structure (98.1 us): single K/V buffer, 2 barriers/k-tile,
// depth-1 register prefetch, setprio around MFMA clusters. Structural ledger:
// 4-wave blocks (125us), 1-barrier dbuf (102us), (q,k)-split (110us) all
// regressed — VALU is the marginal pipe, so this round adds ONLY defer-max
// (T13): skip the unconditional per-tile o_acc/l rescale (32 mults + 4 exp2)
// when the wave-wide max growth <= 8 (exp2-domain: P bounded by 2^8, safe in
// f32 accum; first tile has gr=+inf so the branch initializes m correctly).
// F&31 = (b,h) group (XCD pin: F%8 = g%8); u = F>>5: qt = u (u<8) else 23-u,
// pairing long+short diagonals across co-dispatched blocks. Each wave owns 16
// q-rows; waves fully above the diagonal skip compute (barriers stay
// unconditional). Q prescaled by 192^-0.5*log2e; V is (B,H,128,S) transposed
// so staging is b128-only, bank-uniform. Softmax reductions: DPP row
// all-reduce. Staging: STATIC register arrays (r9: dynamic idx -> scratch 13x).
#define LK 200
#define LV 72
#define LP 72
__global__ __launch_bounds__(512) void flash_k(const BF16* __restrict__ Qt, const BF16* __restrict__ Kt,
                                               const BF16* __restrict__ Vt, BF16* __restrict__ O) {
  __shared__ __align__(16) BF16 Ks[64*LK];    // K tile [kpos][d]        25.6 KB
  __shared__ __align__(16) BF16 Vs[128*LV];   // V^T tile [vd][kpos]     18.4 KB
  __shared__ __align__(16) BF16 Ps[8][16*LP]; // per-wave P [q16][kpos]  18.4 KB
  int tid = threadIdx.x, wave = tid >> 6, lane = tid & 63;
  int lr = lane & 15, quad = lane >> 4;
  int F = blockIdx.x;
  int g = F & 31, u = F >> 5;
  int qt = (u < 8) ? u : 23 - u;      // co-resident pairing: qt + (15-qt)
  int h = g & 15, b = g >> 4;
  const BF16* Qb = Qt + ((long)(b*16 + h) * 2048) * 192;
  const BF16* Kb = Kt + ((long)(b*16 + h) * 2048) * 192;
  const BF16* Vb = Vt + ((long)(b*16 + h) * 128) * 2048;
  const float NEG_INF = -__builtin_inff();

  // staging geometry: K 1536 chunks / 512 thr = 3; V 1024 chunks / 512 thr = 2
  int krow[3], kcol[3];
#pragma unroll
  for (int i = 0; i < 3; i++) {
    int c = tid + 512*i;
    krow[i] = c / 24; kcol[i] = (c % 24) * 8;
  }
  int vrow[2], vcol[2];
#pragma unroll
  for (int i = 0; i < 2; i++) {
    int c = tid + 512*i;
    vrow[i] = c >> 3; vcol[i] = (c & 7) * 8;
  }

  bf16x8 kreg[3], vreg[2];   // depth-1, statically indexed
  auto stage_load = [&](int k0) {
#pragma unroll
    for (int i = 0; i < 3; i++)
      kreg[i] = *(const bf16x8*)(Kb + (long)(k0 + krow[i])*192 + kcol[i]);
#pragma unroll
    for (int i = 0; i < 2; i++)
      vreg[i] = *(const bf16x8*)(Vb + (long)vrow[i]*2048 + k0 + vcol[i]);
  };
  auto stage_store = [&]() {
#pragma unroll
    for (int i = 0; i < 3; i++)
      *(bf16x8*)(Ks + krow[i]*LK + kcol[i]) = kreg[i];
#pragma unroll
    for (int i = 0; i < 2; i++)
      *(bf16x8*)(Vs + vrow[i]*LV + vcol[i]) = vreg[i];
  };

  {
    int q0 = qt * 128;
    int wq0 = q0 + wave*16;   // this wave's first q-row
    bf16x8 qf[6];
    {
      const BF16* qp = Qb + (long)(wq0 + lr) * 192 + quad*8;
#pragma unroll
      for (int f = 0; f < 6; f++) qf[f] = *(const bf16x8*)(qp + f*32);
    }
    float m_i[4], l_i[4];
#pragma unroll
    for (int r = 0; r < 4; r++) { m_i[r] = NEG_INF; l_i[r] = 0.f; }
    floatx4 o_acc[8] = {};
    int nk = 2*qt + 2;
    stage_load(0);
    for (int kt = 0; kt < nk; kt++) {
      __syncthreads();   // prev-iter LDS reads complete
      stage_store();
      __syncthreads();
      if (kt + 1 < nk) stage_load((kt + 1) * 64);  // prefetch overlaps compute
      if (kt*64 > wq0 + 15) continue;  // wave fully above diagonal (masked out)
      floatx4 st[4];
      __builtin_amdgcn_s_setprio(1);
#pragma unroll
      for (int t = 0; t < 4; t++) {
        floatx4 c = {};
#pragma unroll
        for (int f = 0; f < 6; f++) {
          bf16x8 kf = *(const bf16x8*)(Ks + (t*16+lr)*LK + f*32 + quad*8);
          c = __builtin_amdgcn_mfma_f32_16x16x32_bf16(qf[f], kf, c, 0, 0, 0);
        }
        st[t] = c;
      }
      __builtin_amdgcn_s_setprio(0);
      float mt[4];
#pragma unroll
      for (int r = 0; r < 4; r++) mt[r] = NEG_INF;
      if (kt*64 + 63 > wq0) { // diagonal k-tile for this wave: causal mask
        int rbase = wq0 + quad*4 - kt*64;  // row - kbase
#pragma unroll
        for (int t = 0; t < 4; t++) {
          int coff = t*16 + lr;
#pragma unroll
          for (int r = 0; r < 4; r++) {
            float sc = st[t][r];
            if (coff > rbase + r) sc = NEG_INF;
            st[t][r] = sc;
            mt[r] = fmaxf(mt[r], sc);
          }
        }
      } else {
#pragma unroll
        for (int t = 0; t < 4; t++)
#pragma unroll
          for (int r = 0; r < 4; r++) mt[r] = fmaxf(mt[r], st[t][r]);
      }
#pragma unroll
      for (int r = 0; r < 4; r++) mt[r] = row_allmax(mt[r]);
      // defer-max (T13): skip O/l rescale when wave-wide max growth <= 8
      // (exp2 domain: P bounded by 2^8, safe in f32 accum; first tile has
      // gr=+inf -> branch taken -> m initialized, alpha=exp2(-inf)=0).
      float gr = fmaxf(fmaxf(mt[0]-m_i[0], mt[1]-m_i[1]),
                       fmaxf(mt[2]-m_i[2], mt[3]-m_i[3]));
      gr = fmaxf(gr, __shfl_xor(gr, 16));
      gr = fmaxf(gr, __shfl_xor(gr, 32));
      if (gr > 8.f) {
#pragma unroll
        for (int r = 0; r < 4; r++) {
          float mn = fmaxf(m_i[r], mt[r]);
          float alpha = fast_exp2(m_i[r] - mn);
          m_i[r] = mn;
          l_i[r] *= alpha;
#pragma unroll
          for (int v = 0; v < 8; v++) o_acc[v][r] *= alpha;
        }
      }
      float rsum[4];
#pragma unroll
      for (int r = 0; r < 4; r++) rsum[r] = 0.f;
#pragma unroll
      for (int t = 0; t < 4; t++)
#pragma unroll
        for (int r = 0; r < 4; r++) {
          float p = fast_exp2(st[t][r] - m_i[r]);
          st[t][r] = p;
          rsum[r] += p;
        }
#pragma unroll
      for (int r = 0; r < 4; r++) { rsum[r] = row_allsum(rsum[r]); l_i[r] += rsum[r]; }
      // P (C-layout) -> wave-private LDS -> A-layout (no barrier: wave-level ordering)
#pragma unroll
      for (int t = 0; t < 4; t++)
#pragma unroll
        for (int r = 0; r < 4; r++)
          Ps[wave][(quad*4 + r)*LP + t*16 + lr] = f2b(st[t][r]);
      __builtin_amdgcn_s_setprio(1);
#pragma unroll
      for (int kc = 0; kc < 2; kc++) {
        bf16x8 pa = *(const bf16x8*)(&Ps[wave][lr*LP + kc*32 + quad*8]);
#pragma unroll
        for (int v = 0; v < 8; v++) {
          bf16x8 vf = *(const bf16x8*)(&Vs[(v*16+lr)*LV + kc*32 + quad*8]);
          o_acc[v] = __builtin_amdgcn_mfma_f32_16x16x32_bf16(pa, vf, o_acc[v], 0, 0, 0);
        }
      }
      __builtin_amdgcn_s_setprio(0);
    }
    // epilogue: attn out (B,S,H*128) bf16
    long rowb = wq0 + quad*4;
#pragma unroll
    for (int v = 0; v < 8; v++)
#pragma unroll
      for (int r = 0; r < 4; r++) {
        long row = rowb + r;
        O[((long)b*2048 + row)*2048 + h*128 + v*16 + lr] = f2b(o_acc[v][r] / l_i[r]);
      }
  }
}

// ---------------------------------------------------------------- launch
extern "C" void kernel_launch(void* const* d_in, const int* in_sizes, int n_in,
                              void* d_out, int out_size, void* d_ws, size_t ws_size,
                              hipStream_t stream) {
  const float* hidden      = (const float*)d_in[0];
  const float* cosb        = (const float*)d_in[1];
  const float* sinb        = (const float*)d_in[2];
  const float* q_a_W       = (const float*)d_in[3];
  const float* q_a_norm_w  = (const float*)d_in[4];
  const float* q_b_W       = (const float*)d_in[5];
  const float* kv_a_W      = (const float*)d_in[6];
  const float* kv_a_norm_w = (const float*)d_in[7];
  const float* kv_b_W      = (const float*)d_in[8];
  const float* o_W         = (const float*)d_in[9];
  float* out = (float*)d_out;

  const int Mrows = 4096;

  char* ws = (char*)d_ws; size_t off = 0;
  auto alloc = [&](size_t bytes) -> void* {
    void* p = ws + off; off = (off + bytes + 255) & ~(size_t)255; return p;
  };
  BF16* hb    = (BF16*)alloc((size_t)4096*2048*2);
  BF16* Wqakv = (BF16*)alloc((size_t)2112*2048*2);   // rows 0..1536 = q_a_W, 1536..2112 = kv_a_W
  BF16* Wqb   = (BF16*)alloc((size_t)3072*1536*2);
  BF16* Wkvb  = (BF16*)alloc((size_t)4096*512*2);
  BF16* Wo    = (BF16*)alloc((size_t)2048*2048*2);
  float* qakv = (float*)alloc((size_t)4096*2112*4);  // cols 0..1536 = q_a out, 1536..2112 = ckv
  BF16* qan   = (BF16*)alloc((size_t)4096*1536*2);
  BF16* kvn   = (BF16*)alloc((size_t)4096*512*2);
  BF16* Qt    = (BF16*)alloc((size_t)2*16*2048*192*2);
  BF16* Kt    = (BF16*)alloc((size_t)2*16*2048*192*2);
  BF16* Vt    = (BF16*)alloc((size_t)2*16*128*2048*2); // transposed (B,H,128,S)
  BF16* attn  = (BF16*)alloc((size_t)4096*2048*2);

  CastArgs ca;
  ca.src[0] = hidden;  ca.dst[0] = hb;                 ca.n[0] = (long)4096*2048;
  ca.src[1] = q_a_W;   ca.dst[1] = Wqakv;              ca.n[1] = (long)1536*2048;
  ca.src[2] = kv_a_W;  ca.dst[2] = Wqakv + (long)1536*2048; ca.n[2] = (long)576*2048;
  ca.src[3] = q_b_W;   ca.dst[3] = Wqb;                ca.n[3] = (long)3072*1536;
  ca.src[4] = kv_b_W;  ca.dst[4] = Wkvb;               ca.n[4] = (long)4096*512;
  ca.src[5] = o_W;     ca.dst[5] = Wo;                 ca.n[5] = (long)2048*2048;
  cast_multi_k<<<dim3(1024, 6), dim3(256), 0, stream>>>(ca);

  // [q_a | ckv] = hidden @ [q_a_W | kv_a_W].T  (4096 x 2112, K=2048), fp32
  gemm0_k<<<dim3(17, 16), dim3(512), 0, stream>>>(hb, Wqakv, qakv, Mrows, 2112, 2048);

  // fused rmsnorms + k_rot RoPE
  norms_k<<<dim3(4096), dim3(256), 0, stream>>>(qakv, q_a_norm_w, kv_a_norm_w,
                                                cosb, sinb, qan, kvn, Kt);

  // q_b (RoPE+scale -> Qt) and kv_b (scatter -> Kt / Vt^T) in one launch
  gemm_qkv_k<<<dim3(896), dim3(512), 0, stream>>>(qan, Wqb, kvn, Wkvb, cosb, sinb, Qt, Kt, Vt);

  flash_k<<<dim3(512), dim3(512), 0, stream>>>(Qt, Kt, Vt, attn);

  // out = attn @ o_W.T (4096x2048, K=2048), fp32 -> d_out
  gemm0_k<<<dim3(16, 16), dim3(512), 0, stream>>>(attn, Wo, out, Mrows, 2048, 2048);
}

// Round 11
// 449.340 us; speedup vs baseline: 1.0172x; 1.0022x over previous
//
#include <hip/hip_runtime.h>
#include <hip/hip_bf16.h>

// DeepSeek V3 MLA attention forward, MI355X (gfx950).
// B=2, S=2048, D=2048, H=16, NOPE=128, ROPE=64, VDIM=128, QKD=192.

typedef __bf16 bf16x8 __attribute__((ext_vector_type(8)));
typedef float floatx4 __attribute__((ext_vector_type(4)));
#define BF16 __hip_bfloat16

static __device__ __forceinline__ BF16 f2b(float x) { return __float2bfloat16(x); }
static __device__ __forceinline__ unsigned short b2u(BF16 x) { return *(unsigned short*)&x; }
static __device__ __forceinline__ float fast_exp2(float x) { return __builtin_amdgcn_exp2f(x); }

// DPP cross-lane move within a 16-lane row (VALU pipe, ~8 cyc vs ~60+ for ds_swizzle).
template<int CTRL>
static __device__ __forceinline__ float dpp_mov(float x) {
  int xi = __builtin_bit_cast(int, x);
  int yi = __builtin_amdgcn_update_dpp(xi, xi, CTRL, 0xF, 0xF, false);
  return __builtin_bit_cast(float, yi);
}
// all-reduce across the 16 lanes of a DPP row: quad xor1, quad xor2, half-mirror, mirror
static __device__ __forceinline__ float row_allmax(float x) {
  x = fmaxf(x, dpp_mov<0xB1>(x));   // quad_perm [1,0,3,2]
  x = fmaxf(x, dpp_mov<0x4E>(x));   // quad_perm [2,3,0,1]
  x = fmaxf(x, dpp_mov<0x141>(x));  // row_half_mirror
  x = fmaxf(x, dpp_mov<0x140>(x));  // row_mirror
  return x;
}
static __device__ __forceinline__ float row_allsum(float x) {
  x += dpp_mov<0xB1>(x);
  x += dpp_mov<0x4E>(x);
  x += dpp_mov<0x141>(x);
  x += dpp_mov<0x140>(x);
  return x;
}

static __device__ __forceinline__ void load_lds16(const BF16* g, BF16* l) {
  __builtin_amdgcn_global_load_lds((__attribute__((address_space(1))) void*)(void*)g,
                                   (__attribute__((address_space(3))) void*)(void*)l,
                                   16, 0, 0);
}

// T1: bijective XCD-aware block remap (valid when nwg % 8 == 0). Dispatch is
// round-robin over 8 XCDs; after remap each XCD owns a CONTIGUOUS tile chunk
// -> neighboring tiles share A-panels in that XCD's private L2.
static __device__ __forceinline__ int xcd_swz(int bid, int nwg) {
  int cpx = nwg >> 3;
  return (bid & 7) * cpx + (bid >> 3);
}

// ---------------------------------------------------------------- multi-region cast f32->bf16
struct CastArgs {
  const float* src[6];
  BF16* dst[6];
  long n[6];
};
__global__ void cast_multi_k(CastArgs a) {
  int r = blockIdx.y;
  long n = a.n[r];
  const float* __restrict__ x = a.src[r];
  BF16* __restrict__ y = a.dst[r];
  for (long i = ((long)blockIdx.x * 256 + threadIdx.x) * 4; i + 3 < n;
       i += (long)gridDim.x * 1024) {
    float4 v = *(const float4*)(x + i);
    y[i+0] = f2b(v.x); y[i+1] = f2b(v.y); y[i+2] = f2b(v.z); y[i+3] = f2b(v.w);
  }
}

// ---------------------------------------------------------------- NT GEMM v2.1
// C[M][N] = A[M][K]*B[N][K]^T.  256x128 tile, BK=64, 512 thr = 8 waves (4x2),
// per-wave 64x64 output (acc[4][4]).  Double-buffered LDS (96 KB),
// global_load_lds staging with XOR-swizzled source (T2), raw s_barrier +
// counted s_waitcnt vmcnt(6) pipeline (T4), s_setprio around MFMA (T5).
// v2.1: split-cluster ILP -- phase-0 ds_reads issue first (sched_barrier
// pinned), lgkmcnt(8) lets MFMA cluster 0 run while phase-1 reads land
// (DS completes in-order); lgkmcnt(0)+barrier before restaging preserves the
// WAR invariant; vmcnt ledger unchanged.
// OUT_MODE: 0 = fp32 C;  2 = kv scatter -> Kt (scalar) / Vt transposed (8B packed);
//           3 = q RoPE+scale scatter -> Qt (scale includes log2(e) for exp2 softmax).
template<int OUT_MODE>
static __device__ __forceinline__ void gemm_body(
    const BF16* __restrict__ A, const BF16* __restrict__ B, void* __restrict__ C,
    int M, int N, int K, const float* __restrict__ cosb, const float* __restrict__ sinb,
    BF16* __restrict__ P1, BF16* __restrict__ P2, int bx, int by, BF16* As, BF16* Bs) {
  int tid = threadIdx.x, wave = tid >> 6, lane = tid & 63;
  int wr = wave >> 1, wc = wave & 1, lr = lane & 15, quad = lane >> 4;
  long m0 = (long)by * 256, n0 = (long)bx * 128;

  // --- staging descriptors: per thread per K-tile, A = 4 chunks, B = 2 chunks (16B each).
  // chunk c -> tile row r = c>>3, chunk col k = c&7. LDS linear (r,k) receives
  // global chunk (r, k ^ (r&7)) so swizzled reads recover logical columns.
  long asrc[4]; int adst[4];
#pragma unroll
  for (int i = 0; i < 4; i++) {
    int c = wave*64 + lane + 512*i;
    int r = c >> 3, k = c & 7;
    asrc[i] = (m0 + r) * (long)K + ((k ^ (r & 7)) << 3);
    adst[i] = wave*512 + i*4096;          // wave-uniform LDS base (HW adds lane*16B)
  }
  long bsrc[2]; int bdst[2];
#pragma unroll
  for (int i = 0; i < 2; i++) {
    int c = wave*64 + lane + 512*i;
    int r = c >> 3, k = c & 7;
    long bn = n0 + r; if (bn >= N) bn = N - 1;  // N-tail clamp (stores are guarded)
    bsrc[i] = bn * (long)K + ((k ^ (r & 7)) << 3);
    bdst[i] = wave*512 + i*4096;
  }

  auto stage = [&](int bi, int kt) {   // 6 global_load_lds per wave per call
    long k0 = (long)kt << 6;
    BF16* Ad = As + bi*16384;
    BF16* Bd = Bs + bi*8192;
#pragma unroll
    for (int i = 0; i < 4; i++) load_lds16(A + asrc[i] + k0, Ad + adst[i]);
#pragma unroll
    for (int i = 0; i < 2; i++) load_lds16(B + bsrc[i] + k0, Bd + bdst[i]);
  };

  // --- read offsets (row*64 elems; chunk col XORed with row&7 = lr&7)
  int aoff[4], boff[4];
#pragma unroll
  for (int i = 0; i < 4; i++) aoff[i] = (wr*64 + i*16 + lr) * 64;
#pragma unroll
  for (int j = 0; j < 4; j++) boff[j] = (wc*64 + j*16 + lr) * 64;
  int x0 = ((quad    ) ^ (lr & 7)) << 3;   // kk=0: chunks 0..3
  int x1 = ((quad ^ 4) ^ (lr & 7)) << 3;   // kk=1: chunks 4..7

  floatx4 acc[4][4] = {};
  int NT = K >> 6;

  // prologue: stage tiles 0 and 1, wait only tile 0 (12 in flight -> 6)
  stage(0, 0);
  stage(1, 1);
  asm volatile("s_waitcnt vmcnt(6)" ::: "memory");
  __builtin_amdgcn_s_barrier();

  int cur = 0;
  for (int t = 0; t < NT; t++) {
    const BF16* Ab = As + cur*16384;
    const BF16* Bb = Bs + cur*8192;
    bf16x8 a0[4], a1[4], b0[4], b1[4];
    // phase-0 reads first (issue order pinned -> lgkmcnt counts are exact)
#pragma unroll
    for (int i = 0; i < 4; i++) a0[i] = *(const bf16x8*)(Ab + aoff[i] + x0);
#pragma unroll
    for (int j = 0; j < 4; j++) b0[j] = *(const bf16x8*)(Bb + boff[j] + x0);
    __builtin_amdgcn_sched_barrier(0);
#pragma unroll
    for (int i = 0; i < 4; i++) a1[i] = *(const bf16x8*)(Ab + aoff[i] + x1);
#pragma unroll
    for (int j = 0; j < 4; j++) b1[j] = *(const bf16x8*)(Bb + boff[j] + x1);
    // oldest 8 (phase-0) retired; phase-1 reads still in flight under MFMA
    asm volatile("s_waitcnt lgkmcnt(8)" ::: "memory");
    __builtin_amdgcn_sched_barrier(0);   // rule #18: pin MFMA below the wait
    __builtin_amdgcn_s_setprio(1);
#pragma unroll
    for (int i = 0; i < 4; i++)
#pragma unroll
      for (int j = 0; j < 4; j++)
        acc[i][j] = __builtin_amdgcn_mfma_f32_16x16x32_bf16(a0[i], b0[j], acc[i][j], 0, 0, 0);
    __builtin_amdgcn_s_setprio(0);
    // all reads from buf[cur] complete -> free for restaging after the barrier
    asm volatile("s_waitcnt lgkmcnt(0)" ::: "memory");
    __builtin_amdgcn_s_barrier();
    if (t + 2 < NT) stage(cur, t + 2);   // issue-early: latency hides under MFMA
    __builtin_amdgcn_s_setprio(1);
#pragma unroll
    for (int i = 0; i < 4; i++)
#pragma unroll
      for (int j = 0; j < 4; j++)
        acc[i][j] = __builtin_amdgcn_mfma_f32_16x16x32_bf16(a1[i], b1[j], acc[i][j], 0, 0, 0);
    __builtin_amdgcn_s_setprio(0);
    // retire tile t+1's 6 loads (t+2's 6 stay in flight); publish via barrier
    if (t + 2 < NT)      { asm volatile("s_waitcnt vmcnt(6)" ::: "memory"); }
    else if (t + 1 < NT) { asm volatile("s_waitcnt vmcnt(0)" ::: "memory"); }
    __builtin_amdgcn_s_barrier();
    __builtin_amdgcn_sched_barrier(0);
    cur ^= 1;
  }

  long n0w = n0 + wc*64;
  // 192^-0.5 * log2(e): softmax runs in exp2 domain.
  const float SCALE_L2E = 0.104117546f;
#pragma unroll
  for (int i = 0; i < 4; i++) {
    long tok = m0 + wr*64 + i*16 + quad*4;   // 4 consecutive tokens (r=0..3)
    long bb = tok >> 11, s = tok & 2047;
    if (OUT_MODE == 0) {
#pragma unroll
      for (int r = 0; r < 4; r++) {
        long row = tok + r;
#pragma unroll
        for (int j = 0; j < 4; j++) {
          long col = n0w + j*16 + lr;
          if (col < N) ((float*)C)[row*(long)N + col] = acc[i][j][r];
        }
      }
    } else if (OUT_MODE == 2) {
#pragma unroll
      for (int j = 0; j < 4; j++) {
        long col = n0w + j*16 + lr;
        long h = col >> 8, d = col & 255;
        if (d < 128) {
#pragma unroll
          for (int r = 0; r < 4; r++)
            P1[((bb*16 + h)*2048 + s + r)*192 + d] = f2b(acc[i][j][r]);
        } else {
          // Vt transposed (B,H,128,2048): 4 consecutive tokens packed, 8B store
          ushort4 pk;
          pk.x = b2u(f2b(acc[i][j][0])); pk.y = b2u(f2b(acc[i][j][1]));
          pk.z = b2u(f2b(acc[i][j][2])); pk.w = b2u(f2b(acc[i][j][3]));
          *(ushort4*)(P2 + ((bb*16 + h)*128 + d - 128)*2048 + s) = pk;
        }
      }
    } else { // OUT_MODE == 3: q RoPE + scale -> Qt (B,H,S,192)
      bool rope = ((n0w % 192) == 128);
#pragma unroll
      for (int r = 0; r < 4; r++) {
        long row = tok + r;
#pragma unroll
        for (int j = 0; j < 4; j++) {
          long col = n0w + j*16 + lr;
          float x = acc[i][j][r], val;
          if (rope) {
            int id = j*16 + lr;
            float partner = acc[i][j^2][r];
            float rot = (j < 2) ? -partner : partner;
            val = x*cosb[row*64 + id] + rot*sinb[row*64 + id];
          } else {
            val = x;
          }
          long h = col / 192, d = col % 192;
          P1[((bb*16 + h)*2048 + s + r)*192 + d] = f2b(val * SCALE_L2E);
        }
      }
    }
  }
}

__global__ __launch_bounds__(512) void gemm0_k(const BF16* __restrict__ A, const BF16* __restrict__ B,
                                               float* __restrict__ C, int M, int N, int K) {
  __shared__ __align__(16) BF16 As[2*256*64];   // 64 KB
  __shared__ __align__(16) BF16 Bs[2*128*64];   // 32 KB
  int nwg = gridDim.x * gridDim.y;              // 272 and 256: both % 8 == 0
  int lin = blockIdx.y * gridDim.x + blockIdx.x;
  int s = xcd_swz(lin, nwg);
  gemm_body<0>(A, B, C, M, N, K, nullptr, nullptr, nullptr, nullptr,
               s % gridDim.x, s / gridDim.x, As, Bs);
}

// q_b (384 blocks, mode 3) + kv_b (512 blocks, mode 2) in one launch: tails overlap.
__global__ __launch_bounds__(512) void gemm_qkv_k(const BF16* __restrict__ qan, const BF16* __restrict__ Wqb,
                                                  const BF16* __restrict__ kvn, const BF16* __restrict__ Wkvb,
                                                  const float* __restrict__ cosb, const float* __restrict__ sinb,
                                                  BF16* __restrict__ Qt, BF16* __restrict__ Kt,
                                                  BF16* __restrict__ Vt) {
  __shared__ __align__(16) BF16 As[2*256*64];
  __shared__ __align__(16) BF16 Bs[2*128*64];
  int bid = blockIdx.x;
  if (bid < 384) {
    int s = xcd_swz(bid, 384);                  // 384 % 8 == 0, bid%8 = XCD
    gemm_body<3>(qan, Wqb, nullptr, 4096, 3072, 1536, cosb, sinb, Qt, nullptr,
                 s % 24, s / 24, As, Bs);
  } else {
    bid -= 384;                                  // 384%8==0 -> bid%8 still = XCD
    int s = xcd_swz(bid, 512);
    gemm_body<2>(kvn, Wkvb, nullptr, 4096, 4096, 512, nullptr, nullptr, Kt, Vt,
                 s % 32, s / 32, As, Bs);
  }
}

// ---------------------------------------------------------------- fused: rmsnorm(1536) + rmsnorm(512) + k_rot RoPE
// One block per token row of qakv (stride 2112: [q_a 1536 | ckv 512 | krot 64]).
__global__ __launch_bounds__(256) void norms_k(const float* __restrict__ qakv,
                                               const float* __restrict__ qw, const float* __restrict__ kw,
                                               const float* __restrict__ cosb, const float* __restrict__ sinb,
                                               BF16* __restrict__ qan, BF16* __restrict__ kvn,
                                               BF16* __restrict__ Kt) {
  long row = blockIdx.x;
  const float* xr = qakv + row * 2112;
  int tid = threadIdx.x;
  __shared__ float red[4];
  // ---- rmsnorm D=1536 -> qan
  {
    float ss = 0.f;
    for (int i = tid*4; i < 1536; i += 1024) {
      float4 v = *(const float4*)(xr + i);
      ss += v.x*v.x + v.y*v.y + v.z*v.z + v.w*v.w;
    }
#pragma unroll
    for (int off = 32; off > 0; off >>= 1) ss += __shfl_down(ss, off);
    if ((tid & 63) == 0) red[tid >> 6] = ss;
    __syncthreads();
    float rs = rsqrtf((red[0]+red[1]+red[2]+red[3]) / 1536.f + 1e-6f);
    BF16* yr = qan + row * 1536;
    for (int i = tid*4; i < 1536; i += 1024) {
      float4 v = *(const float4*)(xr + i);
      yr[i+0] = f2b(v.x * qw[i+0] * rs);
      yr[i+1] = f2b(v.y * qw[i+1] * rs);
      yr[i+2] = f2b(v.z * qw[i+2] * rs);
      yr[i+3] = f2b(v.w * qw[i+3] * rs);
    }
  }
  __syncthreads();
  // ---- rmsnorm D=512 (offset 1536) -> kvn
  {
    float ss = 0.f;
    for (int i = tid*4; i < 512; i += 1024) {
      float4 v = *(const float4*)(xr + 1536 + i);
      ss += v.x*v.x + v.y*v.y + v.z*v.z + v.w*v.w;
    }
#pragma unroll
    for (int off = 32; off > 0; off >>= 1) ss += __shfl_down(ss, off);
    if ((tid & 63) == 0) red[tid >> 6] = ss;
    __syncthreads();
    float rs = rsqrtf((red[0]+red[1]+red[2]+red[3]) / 512.f + 1e-6f);
    BF16* yr = kvn + row * 512;
    for (int i = tid*4; i < 512; i += 1024) {
      float4 v = *(const float4*)(xr + 1536 + i);
      yr[i+0] = f2b(v.x * kw[i+0] * rs);
      yr[i+1] = f2b(v.y * kw[i+1] * rs);
      yr[i+2] = f2b(v.z * kw[i+2] * rs);
      yr[i+3] = f2b(v.w * kw[i+3] * rs);
    }
  }
  // ---- k_rot RoPE -> Kt[...,128:192] broadcast to all 16 heads
  if (tid < 64) {
    int i = tid;
    const float* kr = xr + 2048;
    float x = kr[i];
    float rot = (i < 32) ? -kr[i + 32] : kr[i - 32];
    BF16 v = f2b(x * cosb[row*64 + i] + rot * sinb[row*64 + i]);
    long b = row >> 11, s = row & 2047;
    long base = ((b*16)*2048 + s)*192 + 128 + i;
#pragma unroll
    for (int h = 0; h < 16; h++) Kt[base + (long)h*2048*192] = v;
  }
}

// ---------------------------------------------------------------- causal flash attention
// grid 512, 512 threads (8 waves). One q-tile (128 rows) per block — the
// best-measured structure (R3: 98.1 us), restored EXACTLY. Structural ledger
// (all measured, all worse): 4-wave blocks 125, (q,k)-split 110, defer-max
// 104, 1-barrier dbuf 102. This kernel is a converged local minimum at
// 2 waves/SIMD; leave it alone.
// F&31 = (b,h) group (XCD pin: F%8 = g%8); u = F>>5: qt = u (u<8) else 23-u,
// pairing long+short diagonals across co-dispatched blocks. Each wave owns 16
// q-rows; waves fully above the diagonal skip compute (barriers stay
// unconditional). Q prescaled by 192^-0.5*log2e; V is (B,H,128,S) transposed
// so staging is b128-only, bank-uniform. Softmax reductions: DPP row
// all-reduce. Staging: STATIC register arrays (r9: dynamic idx -> scratch 13x).
#define LK 200
#define LV 72
#define LP 72
__global__ __launch_bounds__(512) void flash_k(const BF16* __restrict__ Qt, const BF16* __restrict__ Kt,
                                               const BF16* __restrict__ Vt, BF16* __restrict__ O) {
  __shared__ __align__(16) BF16 Ks[64*LK];    // K tile [kpos][d]        25.6 KB
  __shared__ __align__(16) BF16 Vs[128*LV];   // V^T tile [vd][kpos]     18.4 KB
  __shared__ __align__(16) BF16 Ps[8][16*LP]; // per-wave P [q16][kpos]  18.4 KB
  int tid = threadIdx.x, wave = tid >> 6, lane = tid & 63;
  int lr = lane & 15, quad = lane >> 4;
  int F = blockIdx.x;
  int g = F & 31, u = F >> 5;
  int qt = (u < 8) ? u : 23 - u;      // co-resident pairing: qt + (15-qt)
  int h = g & 15, b = g >> 4;
  const BF16* Qb = Qt + ((long)(b*16 + h) * 2048) * 192;
  const BF16* Kb = Kt + ((long)(b*16 + h) * 2048) * 192;
  const BF16* Vb = Vt + ((long)(b*16 + h) * 128) * 2048;
  const float NEG_INF = -__builtin_inff();

  // staging geometry: K 1536 chunks / 512 thr = 3; V 1024 chunks / 512 thr = 2
  int krow[3], kcol[3];
#pragma unroll
  for (int i = 0; i < 3; i++) {
    int c = tid + 512*i;
    krow[i] = c / 24; kcol[i] = (c % 24) * 8;
  }
  int vrow[2], vcol[2];
#pragma unroll
  for (int i = 0; i < 2; i++) {
    int c = tid + 512*i;
    vrow[i] = c >> 3; vcol[i] = (c & 7) * 8;
  }

  bf16x8 kreg[3], vreg[2];   // depth-1, statically indexed
  auto stage_load = [&](int k0) {
#pragma unroll
    for (int i = 0; i < 3; i++)
      kreg[i] = *(const bf16x8*)(Kb + (long)(k0 + krow[i])*192 + kcol[i]);
#pragma unroll
    for (int i = 0; i < 2; i++)
      vreg[i] = *(const bf16x8*)(Vb + (long)vrow[i]*2048 + k0 + vcol[i]);
  };
  auto stage_store = [&]() {
#pragma unroll
    for (int i = 0; i < 3; i++)
      *(bf16x8*)(Ks + krow[i]*LK + kcol[i]) = kreg[i];
#pragma unroll
    for (int i = 0; i < 2; i++)
      *(bf16x8*)(Vs + vrow[i]*LV + vcol[i]) = vreg[i];
  };

  {
    int q0 = qt * 128;
    int wq0 = q0 + wave*16;   // this wave's first q-row
    bf16x8 qf[6];
    {
      const BF16* qp = Qb + (long)(wq0 + lr) * 192 + quad*8;
#pragma unroll
      for (int f = 0; f < 6; f++) qf[f] = *(const bf16x8*)(qp + f*32);
    }
    float m_i[4], l_i[4];
#pragma unroll
    for (int r = 0; r < 4; r++) { m_i[r] = NEG_INF; l_i[r] = 0.f; }
    floatx4 o_acc[8] = {};
    int nk = 2*qt + 2;
    stage_load(0);
    for (int kt = 0; kt < nk; kt++) {
      __syncthreads();   // prev-iter LDS reads complete
      stage_store();
      __syncthreads();
      if (kt + 1 < nk) stage_load((kt + 1) * 64);  // prefetch overlaps compute
      if (kt*64 > wq0 + 15) continue;  // wave fully above diagonal (masked out)
      floatx4 st[4];
      __builtin_amdgcn_s_setprio(1);
#pragma unroll
      for (int t = 0; t < 4; t++) {
        floatx4 c = {};
#pragma unroll
        for (int f = 0; f < 6; f++) {
          bf16x8 kf = *(const bf16x8*)(Ks + (t*16+lr)*LK + f*32 + quad*8);
          c = __builtin_amdgcn_mfma_f32_16x16x32_bf16(qf[f], kf, c, 0, 0, 0);
        }
        st[t] = c;
      }
      __builtin_amdgcn_s_setprio(0);
      float mt[4];
#pragma unroll
      for (int r = 0; r < 4; r++) mt[r] = NEG_INF;
      if (kt*64 + 63 > wq0) { // diagonal k-tile for this wave: causal mask
        int rbase = wq0 + quad*4 - kt*64;  // row - kbase
#pragma unroll
        for (int t = 0; t < 4; t++) {
          int coff = t*16 + lr;
#pragma unroll
          for (int r = 0; r < 4; r++) {
            float sc = st[t][r];
            if (coff > rbase + r) sc = NEG_INF;
            st[t][r] = sc;
            mt[r] = fmaxf(mt[r], sc);
          }
        }
      } else {
#pragma unroll
        for (int t = 0; t < 4; t++)
#pragma unroll
          for (int r = 0; r < 4; r++) mt[r] = fmaxf(mt[r], st[t][r]);
      }
#pragma unroll
      for (int r = 0; r < 4; r++) mt[r] = row_allmax(mt[r]);
      float alpha[4], rsum[4];
#pragma unroll
      for (int r = 0; r < 4; r++) {
        float mn = fmaxf(m_i[r], mt[r]);
        alpha[r] = fast_exp2(m_i[r] - mn);
        m_i[r] = mn;
        rsum[r] = 0.f;
      }
#pragma unroll
      for (int t = 0; t < 4; t++)
#pragma unroll
        for (int r = 0; r < 4; r++) {
          float p = fast_exp2(st[t][r] - m_i[r]);
          st[t][r] = p;
          rsum[r] += p;
        }
#pragma unroll
      for (int r = 0; r < 4; r++) rsum[r] = row_allsum(rsum[r]);
#pragma unroll
      for (int r = 0; r < 4; r++) l_i[r] = l_i[r]*alpha[r] + rsum[r];
#pragma unroll
      for (int v = 0; v < 8; v++)
#pragma unroll
        for (int r = 0; r < 4; r++) o_acc[v][r] *= alpha[r];
      // P (C-layout) -> wave-private LDS -> A-layout (no barrier: wave-level ordering)
#pragma unroll
      for (int t = 0; t < 4; t++)
#pragma unroll
        for (int r = 0; r < 4; r++)
          Ps[wave][(quad*4 + r)*LP + t*16 + lr] = f2b(st[t][r]);
      __builtin_amdgcn_s_setprio(1);
#pragma unroll
      for (int kc = 0; kc < 2; kc++) {
        bf16x8 pa = *(const bf16x8*)(&Ps[wave][lr*LP + kc*32 + quad*8]);
#pragma unroll
        for (int v = 0; v < 8; v++) {
          bf16x8 vf = *(const bf16x8*)(&Vs[(v*16+lr)*LV + kc*32 + quad*8]);
          o_acc[v] = __builtin_amdgcn_mfma_f32_16x16x32_bf16(pa, vf, o_acc[v], 0, 0, 0);
        }
      }
      __builtin_amdgcn_s_setprio(0);
    }
    // epilogue: attn out (B,S,H*128) bf16
    long rowb = wq0 + quad*4;
#pragma unroll
    for (int v = 0; v < 8; v++)
#pragma unroll
      for (int r = 0; r < 4; r++) {
        long row = rowb + r;
        O[((long)b*2048 + row)*2048 + h*128 + v*16 + lr] = f2b(o_acc[v][r] / l_i[r]);
      }
  }
}

// ---------------------------------------------------------------- launch
extern "C" void kernel_launch(void* const* d_in, const int* in_sizes, int n_in,
                              void* d_out, int out_size, void* d_ws, size_t ws_size,
                              hipStream_t stream) {
  const float* hidden      = (const float*)d_in[0];
  const float* cosb        = (const float*)d_in[1];
  const float* sinb        = (const float*)d_in[2];
  const float* q_a_W       = (const float*)d_in[3];
  const float* q_a_norm_w  = (const float*)d_in[4];
  const float* q_b_W       = (const float*)d_in[5];
  const float* kv_a_W      = (const float*)d_in[6];
  const float* kv_a_norm_w = (const float*)d_in[7];
  const float* kv_b_W      = (const float*)d_in[8];
  const float* o_W         = (const float*)d_in[9];
  float* out = (float*)d_out;

  const int Mrows = 4096;

  char* ws = (char*)d_ws; size_t off = 0;
  auto alloc = [&](size_t bytes) -> void* {
    void* p = ws + off; off = (off + bytes + 255) & ~(size_t)255; return p;
  };
  BF16* hb    = (BF16*)alloc((size_t)4096*2048*2);
  BF16* Wqakv = (BF16*)alloc((size_t)2112*2048*2);   // rows 0..1536 = q_a_W, 1536..2112 = kv_a_W
  BF16* Wqb   = (BF16*)alloc((size_t)3072*1536*2);
  BF16* Wkvb  = (BF16*)alloc((size_t)4096*512*2);
  BF16* Wo    = (BF16*)alloc((size_t)2048*2048*2);
  float* qakv = (float*)alloc((size_t)4096*2112*4);  // cols 0..1536 = q_a out, 1536..2112 = ckv
  BF16* qan   = (BF16*)alloc((size_t)4096*1536*2);
  BF16* kvn   = (BF16*)alloc((size_t)4096*512*2);
  BF16* Qt    = (BF16*)alloc((size_t)2*16*2048*192*2);
  BF16* Kt    = (BF16*)alloc((size_t)2*16*2048*192*2);
  BF16* Vt    = (BF16*)alloc((size_t)2*16*128*2048*2); // transposed (B,H,128,S)
  BF16* attn  = (BF16*)alloc((size_t)4096*2048*2);

  CastArgs ca;
  ca.src[0] = hidden;  ca.dst[0] = hb;                 ca.n[0] = (long)4096*2048;
  ca.src[1] = q_a_W;   ca.dst[1] = Wqakv;              ca.n[1] = (long)1536*2048;
  ca.src[2] = kv_a_W;  ca.dst[2] = Wqakv + (long)1536*2048; ca.n[2] = (long)576*2048;
  ca.src[3] = q_b_W;   ca.dst[3] = Wqb;                ca.n[3] = (long)3072*1536;
  ca.src[4] = kv_b_W;  ca.dst[4] = Wkvb;               ca.n[4] = (long)4096*512;
  ca.src[5] = o_W;     ca.dst[5] = Wo;                 ca.n[5] = (long)2048*2048;
  cast_multi_k<<<dim3(1024, 6), dim3(256), 0, stream>>>(ca);

  // [q_a | ckv] = hidden @ [q_a_W | kv_a_W].T  (4096 x 2112, K=2048), fp32
  gemm0_k<<<dim3(17, 16), dim3(512), 0, stream>>>(hb, Wqakv, qakv, Mrows, 2112, 2048);

  // fused rmsnorms + k_rot RoPE
  norms_k<<<dim3(4096), dim3(256), 0, stream>>>(qakv, q_a_norm_w, kv_a_norm_w,
                                                cosb, sinb, qan, kvn, Kt);

  // q_b (RoPE+scale -> Qt) and kv_b (scatter -> Kt / Vt^T) in one launch
  gemm_qkv_k<<<dim3(896), dim3(512), 0, stream>>>(qan, Wqb, kvn, Wkvb, cosb, sinb, Qt, Kt, Vt);

  flash_k<<<dim3(512), dim3(512), 0, stream>>>(Qt, Kt, Vt, attn);

  // out = attn @ o_W.T (4096x2048, K=2048), fp32 -> d_out
  gemm0_k<<<dim3(16, 16), dim3(512), 0, stream>>>(attn, Wo, out, Mrows, 2048, 2048);
}

// Round 12
// 439.179 us; speedup vs baseline: 1.0407x; 1.0231x over previous
//
#include <hip/hip_runtime.h>
#include <hip/hip_bf16.h>

// DeepSeek V3 MLA attention forward, MI355X (gfx950).
// B=2, S=2048, D=2048, H=16, NOPE=128, ROPE=64, VDIM=128, QKD=192.

typedef __bf16 bf16x8 __attribute__((ext_vector_type(8)));
typedef float floatx4 __attribute__((ext_vector_type(4)));
#define BF16 __hip_bfloat16

static __device__ __forceinline__ BF16 f2b(float x) { return __float2bfloat16(x); }
static __device__ __forceinline__ unsigned short b2u(BF16 x) { return *(unsigned short*)&x; }
static __device__ __forceinline__ float fast_exp2(float x) { return __builtin_amdgcn_exp2f(x); }

// DPP cross-lane move within a 16-lane row (VALU pipe, ~8 cyc vs ~60+ for ds_swizzle).
template<int CTRL>
static __device__ __forceinline__ float dpp_mov(float x) {
  int xi = __builtin_bit_cast(int, x);
  int yi = __builtin_amdgcn_update_dpp(xi, xi, CTRL, 0xF, 0xF, false);
  return __builtin_bit_cast(float, yi);
}
// all-reduce across the 16 lanes of a DPP row: quad xor1, quad xor2, half-mirror, mirror
static __device__ __forceinline__ float row_allmax(float x) {
  x = fmaxf(x, dpp_mov<0xB1>(x));   // quad_perm [1,0,3,2]
  x = fmaxf(x, dpp_mov<0x4E>(x));   // quad_perm [2,3,0,1]
  x = fmaxf(x, dpp_mov<0x141>(x));  // row_half_mirror
  x = fmaxf(x, dpp_mov<0x140>(x));  // row_mirror
  return x;
}
static __device__ __forceinline__ float row_allsum(float x) {
  x += dpp_mov<0xB1>(x);
  x += dpp_mov<0x4E>(x);
  x += dpp_mov<0x141>(x);
  x += dpp_mov<0x140>(x);
  return x;
}

static __device__ __forceinline__ void load_lds16(const BF16* g, BF16* l) {
  __builtin_amdgcn_global_load_lds((__attribute__((address_space(1))) void*)(void*)g,
                                   (__attribute__((address_space(3))) void*)(void*)l,
                                   16, 0, 0);
}

// ---------------------------------------------------------------- multi-region cast f32->bf16
struct CastArgs {
  const float* src[6];
  BF16* dst[6];
  long n[6];
};
__global__ void cast_multi_k(CastArgs a) {
  int r = blockIdx.y;
  long n = a.n[r];
  const float* __restrict__ x = a.src[r];
  BF16* __restrict__ y = a.dst[r];
  for (long i = ((long)blockIdx.x * 256 + threadIdx.x) * 4; i + 3 < n;
       i += (long)gridDim.x * 1024) {
    float4 v = *(const float4*)(x + i);
    y[i+0] = f2b(v.x); y[i+1] = f2b(v.y); y[i+2] = f2b(v.z); y[i+3] = f2b(v.w);
  }
}

// ---------------------------------------------------------------- NT GEMM v2.2
// C[M][N] = A[M][K]*B[N][K]^T.  256x128 tile, BK=64, 512 thr = 8 waves (4x2),
// per-wave 64x64 output (acc[4][4]).  Double-buffered LDS (96 KB, single smem
// block: As = smem[0:32768], Bs = smem[32768:49152]), global_load_lds staging
// with XOR-swizzled source (T2), raw s_barrier + counted s_waitcnt vmcnt(6)
// pipeline (T4), s_setprio around MFMA (T5). Inner loop = R3-exact (v2.1's
// split-cluster lgkmcnt + XCD swizzle measured NULL, reverted).
// v2.2: modes 2/3 epilogue rebuilt as LDS-transpose -> coalesced stores.
// Old epilogue: scalar 2B stores in 32-B quarter-line runs (Qt/Kt) and 8-B
// stores at 4-KB stride (Vt) — ~58 MB of scattered traffic. New: acc packs
// ushort4 along tokens into transposed Ct[col][260] (b64 LDS writes), one
// barrier, then lanes stream along the contiguous global dim (d for Qt/Kt,
// s for Vt) in 128-B runs. Same bytes, bit-exact bf16, ~4-8x fewer txns.
// Mode-2 blocks are pure-Kt (bx even) or pure-Vt (bx odd): n0%256 in {0,128}.
// OUT_MODE: 0 = fp32 C (direct stores, 64-B runs — unchanged);
//           2 = kv scatter -> Kt / Vt;  3 = q RoPE+scale -> Qt.
template<int OUT_MODE>
static __device__ __forceinline__ void gemm_body(
    const BF16* __restrict__ A, const BF16* __restrict__ B, void* __restrict__ C,
    int M, int N, int K, const float* __restrict__ cosb, const float* __restrict__ sinb,
    BF16* __restrict__ P1, BF16* __restrict__ P2, int bx, int by, BF16* smem) {
  BF16* As = smem;               // 2*256*64 = 32768 elems (64 KB)
  BF16* Bs = smem + 32768;       // 2*128*64 = 16384 elems (32 KB)
  int tid = threadIdx.x, wave = tid >> 6, lane = tid & 63;
  int wr = wave >> 1, wc = wave & 1, lr = lane & 15, quad = lane >> 4;
  long m0 = (long)by * 256, n0 = (long)bx * 128;

  // --- staging descriptors: per thread per K-tile, A = 4 chunks, B = 2 chunks (16B each).
  // chunk c -> tile row r = c>>3, chunk col k = c&7. LDS linear (r,k) receives
  // global chunk (r, k ^ (r&7)) so swizzled reads recover logical columns.
  long asrc[4]; int adst[4];
#pragma unroll
  for (int i = 0; i < 4; i++) {
    int c = wave*64 + lane + 512*i;
    int r = c >> 3, k = c & 7;
    asrc[i] = (m0 + r) * (long)K + ((k ^ (r & 7)) << 3);
    adst[i] = wave*512 + i*4096;          // wave-uniform LDS base (HW adds lane*16B)
  }
  long bsrc[2]; int bdst[2];
#pragma unroll
  for (int i = 0; i < 2; i++) {
    int c = wave*64 + lane + 512*i;
    int r = c >> 3, k = c & 7;
    long bn = n0 + r; if (bn >= N) bn = N - 1;  // N-tail clamp (stores are guarded)
    bsrc[i] = bn * (long)K + ((k ^ (r & 7)) << 3);
    bdst[i] = wave*512 + i*4096;
  }

  auto stage = [&](int bi, int kt) {   // 6 global_load_lds per wave per call
    long k0 = (long)kt << 6;
    BF16* Ad = As + bi*16384;
    BF16* Bd = Bs + bi*8192;
#pragma unroll
    for (int i = 0; i < 4; i++) load_lds16(A + asrc[i] + k0, Ad + adst[i]);
#pragma unroll
    for (int i = 0; i < 2; i++) load_lds16(B + bsrc[i] + k0, Bd + bdst[i]);
  };

  // --- read offsets (row*64 elems; chunk col XORed with row&7 = lr&7)
  int aoff[4], boff[4];
#pragma unroll
  for (int i = 0; i < 4; i++) aoff[i] = (wr*64 + i*16 + lr) * 64;
#pragma unroll
  for (int j = 0; j < 4; j++) boff[j] = (wc*64 + j*16 + lr) * 64;
  int x0 = ((quad    ) ^ (lr & 7)) << 3;   // kk=0: chunks 0..3
  int x1 = ((quad ^ 4) ^ (lr & 7)) << 3;   // kk=1: chunks 4..7

  floatx4 acc[4][4] = {};
  int NT = K >> 6;

  // prologue: stage tiles 0 and 1, wait only tile 0 (12 in flight -> 6)
  stage(0, 0);
  stage(1, 1);
  asm volatile("s_waitcnt vmcnt(6)" ::: "memory");
  __builtin_amdgcn_s_barrier();

  int cur = 0;
  for (int t = 0; t < NT; t++) {
    const BF16* Ab = As + cur*16384;
    const BF16* Bb = Bs + cur*8192;
    bf16x8 a0[4], a1[4], b0[4], b1[4];
#pragma unroll
    for (int i = 0; i < 4; i++) {
      a0[i] = *(const bf16x8*)(Ab + aoff[i] + x0);
      a1[i] = *(const bf16x8*)(Ab + aoff[i] + x1);
    }
#pragma unroll
    for (int j = 0; j < 4; j++) {
      b0[j] = *(const bf16x8*)(Bb + boff[j] + x0);
      b1[j] = *(const bf16x8*)(Bb + boff[j] + x1);
    }
    // all fragments in regs -> buf[cur] is free for restaging after this barrier
    asm volatile("s_waitcnt lgkmcnt(0)" ::: "memory");
    __builtin_amdgcn_s_barrier();
    if (t + 2 < NT) stage(cur, t + 2);   // issue-early: latency hides under MFMA
    __builtin_amdgcn_s_setprio(1);
#pragma unroll
    for (int i = 0; i < 4; i++)
#pragma unroll
      for (int j = 0; j < 4; j++)
        acc[i][j] = __builtin_amdgcn_mfma_f32_16x16x32_bf16(a0[i], b0[j], acc[i][j], 0, 0, 0);
#pragma unroll
    for (int i = 0; i < 4; i++)
#pragma unroll
      for (int j = 0; j < 4; j++)
        acc[i][j] = __builtin_amdgcn_mfma_f32_16x16x32_bf16(a1[i], b1[j], acc[i][j], 0, 0, 0);
    __builtin_amdgcn_s_setprio(0);
    // retire tile t+1's 6 loads (t+2's 6 stay in flight); publish via barrier
    if (t + 2 < NT)      { asm volatile("s_waitcnt vmcnt(6)" ::: "memory"); }
    else if (t + 1 < NT) { asm volatile("s_waitcnt vmcnt(0)" ::: "memory"); }
    __builtin_amdgcn_s_barrier();
    __builtin_amdgcn_sched_barrier(0);
    cur ^= 1;
  }

  // 192^-0.5 * log2(e): softmax runs in exp2 domain.
  const float SCALE_L2E = 0.104117546f;
  if (OUT_MODE == 0) {
    long n0w = n0 + wc*64;
#pragma unroll
    for (int i = 0; i < 4; i++) {
      long tok = m0 + wr*64 + i*16 + quad*4;   // 4 consecutive tokens (r=0..3)
#pragma unroll
      for (int r = 0; r < 4; r++) {
        long row = tok + r;
#pragma unroll
        for (int j = 0; j < 4; j++) {
          long col = n0w + j*16 + lr;
          if (col < N) ((float*)C)[row*(long)N + col] = acc[i][j][r];
        }
      }
    }
  } else {
    // ---- coalesced epilogue via LDS transpose (modes 2 & 3) ----
    // Ct[col][row] transposed, row-stride 260 elems (b64-aligned, bank-spread):
    // 128*260*2 = 66,560 B <= 96 KB smem (main loop done; all LDS reads drained
    // by the final lgkmcnt(0)+barrier, so smem is dead and reusable).
    BF16* Ct = smem;
    bool rope = (OUT_MODE == 3) && (((n0 + wc*64) % 192) == 128);
#pragma unroll
    for (int i = 0; i < 4; i++) {
#pragma unroll
      for (int j = 0; j < 4; j++) {
        ushort4 pk;
#pragma unroll
        for (int r = 0; r < 4; r++) {
          float val = acc[i][j][r];
          if (OUT_MODE == 3) {
            if (rope) {
              int id = j*16 + lr;
              long row = m0 + wr*64 + i*16 + quad*4 + r;
              float partner = acc[i][j^2][r];
              float rot = (j < 2) ? -partner : partner;
              val = val*cosb[row*64 + id] + rot*sinb[row*64 + id];
            }
            val *= SCALE_L2E;
          }
          ((unsigned short*)&pk)[r] = b2u(f2b(val));
        }
        int cl = wc*64 + j*16 + lr;
        int r0 = wr*64 + i*16 + quad*4;
        *(ushort4*)(Ct + cl*260 + r0) = pk;   // 8-B aligned: 260%4==0, r0%4==0
      }
    }
    __syncthreads();
    int tok0 = (int)m0;
    long bb = (long)(tok0 >> 11);     // const per block: m0%2048 + 255 < 2048
    int s0 = tok0 & 2047;
    if (OUT_MODE == 3 || ((n0 & 255) == 0)) {
      // Qt or Kt: lanes stream along d (contiguous in (B,H,S,192) layout).
      long base[2];
#pragma unroll
      for (int cc = 0; cc < 2; cc++) {
        long gcol = n0 + cc*64 + lane;
        long hh = (OUT_MODE == 3) ? (gcol / 192) : (gcol >> 8);
        long dd = (OUT_MODE == 3) ? (gcol % 192) : (gcol & 255);
        base[cc] = ((bb*16 + hh)*2048 + s0) * 192 + dd;
      }
      for (int t = 0; t < 32; t++) {
        int rw = wave*32 + t;
#pragma unroll
        for (int cc = 0; cc < 2; cc++) {
          BF16 v = Ct[(cc*64 + lane)*260 + rw];
          P1[base[cc] + (long)rw*192] = v;   // 64 lanes -> 128-B runs
        }
      }
    } else {
      // Vt (B,H,128,S): lanes stream along s (contiguous).
      long hh = n0 >> 8;
#pragma unroll
      for (int t = 0; t < 16; t++) {
        int cl = wave*16 + t;
        long vbase = ((bb*16 + hh)*128 + cl)*2048 + s0;
#pragma unroll
        for (int rr = 0; rr < 4; rr++) {
          BF16 v = Ct[cl*260 + rr*64 + lane];
          P2[vbase + rr*64 + lane] = v;      // 64 lanes -> 128-B runs
        }
      }
    }
  }
}

__global__ __launch_bounds__(512) void gemm0_k(const BF16* __restrict__ A, const BF16* __restrict__ B,
                                               float* __restrict__ C, int M, int N, int K) {
  __shared__ __align__(16) BF16 smem[49152];   // 96 KB: As | Bs (and Ct alias)
  gemm_body<0>(A, B, C, M, N, K, nullptr, nullptr, nullptr, nullptr,
               blockIdx.x, blockIdx.y, smem);
}

// q_b (384 blocks, mode 3) + kv_b (512 blocks, mode 2) in one launch: tails overlap.
__global__ __launch_bounds__(512) void gemm_qkv_k(const BF16* __restrict__ qan, const BF16* __restrict__ Wqb,
                                                  const BF16* __restrict__ kvn, const BF16* __restrict__ Wkvb,
                                                  const float* __restrict__ cosb, const float* __restrict__ sinb,
                                                  BF16* __restrict__ Qt, BF16* __restrict__ Kt,
                                                  BF16* __restrict__ Vt) {
  __shared__ __align__(16) BF16 smem[49152];
  int bid = blockIdx.x;
  if (bid < 384) {
    gemm_body<3>(qan, Wqb, nullptr, 4096, 3072, 1536, cosb, sinb, Qt, nullptr,
                 bid % 24, bid / 24, smem);
  } else {
    bid -= 384;
    gemm_body<2>(kvn, Wkvb, nullptr, 4096, 4096, 512, nullptr, nullptr, Kt, Vt,
                 bid % 32, bid / 32, smem);
  }
}

// ---------------------------------------------------------------- fused: rmsnorm(1536) + rmsnorm(512) + k_rot RoPE
// One block per token row of qakv (stride 2112: [q_a 1536 | ckv 512 | krot 64]).
__global__ __launch_bounds__(256) void norms_k(const float* __restrict__ qakv,
                                               const float* __restrict__ qw, const float* __restrict__ kw,
                                               const float* __restrict__ cosb, const float* __restrict__ sinb,
                                               BF16* __restrict__ qan, BF16* __restrict__ kvn,
                                               BF16* __restrict__ Kt) {
  long row = blockIdx.x;
  const float* xr = qakv + row * 2112;
  int tid = threadIdx.x;
  __shared__ float red[4];
  // ---- rmsnorm D=1536 -> qan
  {
    float ss = 0.f;
    for (int i = tid*4; i < 1536; i += 1024) {
      float4 v = *(const float4*)(xr + i);
      ss += v.x*v.x + v.y*v.y + v.z*v.z + v.w*v.w;
    }
#pragma unroll
    for (int off = 32; off > 0; off >>= 1) ss += __shfl_down(ss, off);
    if ((tid & 63) == 0) red[tid >> 6] = ss;
    __syncthreads();
    float rs = rsqrtf((red[0]+red[1]+red[2]+red[3]) / 1536.f + 1e-6f);
    BF16* yr = qan + row * 1536;
    for (int i = tid*4; i < 1536; i += 1024) {
      float4 v = *(const float4*)(xr + i);
      yr[i+0] = f2b(v.x * qw[i+0] * rs);
      yr[i+1] = f2b(v.y * qw[i+1] * rs);
      yr[i+2] = f2b(v.z * qw[i+2] * rs);
      yr[i+3] = f2b(v.w * qw[i+3] * rs);
    }
  }
  __syncthreads();
  // ---- rmsnorm D=512 (offset 1536) -> kvn
  {
    float ss = 0.f;
    for (int i = tid*4; i < 512; i += 1024) {
      float4 v = *(const float4*)(xr + 1536 + i);
      ss += v.x*v.x + v.y*v.y + v.z*v.z + v.w*v.w;
    }
#pragma unroll
    for (int off = 32; off > 0; off >>= 1) ss += __shfl_down(ss, off);
    if ((tid & 63) == 0) red[tid >> 6] = ss;
    __syncthreads();
    float rs = rsqrtf((red[0]+red[1]+red[2]+red[3]) / 512.f + 1e-6f);
    BF16* yr = kvn + row * 512;
    for (int i = tid*4; i < 512; i += 1024) {
      float4 v = *(const float4*)(xr + 1536 + i);
      yr[i+0] = f2b(v.x * kw[i+0] * rs);
      yr[i+1] = f2b(v.y * kw[i+1] * rs);
      yr[i+2] = f2b(v.z * kw[i+2] * rs);
      yr[i+3] = f2b(v.w * kw[i+3] * rs);
    }
  }
  // ---- k_rot RoPE -> Kt[...,128:192] broadcast to all 16 heads
  if (tid < 64) {
    int i = tid;
    const float* kr = xr + 2048;
    float x = kr[i];
    float rot = (i < 32) ? -kr[i + 32] : kr[i - 32];
    BF16 v = f2b(x * cosb[row*64 + i] + rot * sinb[row*64 + i]);
    long b = row >> 11, s = row & 2047;
    long base = ((b*16)*2048 + s)*192 + 128 + i;
#pragma unroll
    for (int h = 0; h < 16; h++) Kt[base + (long)h*2048*192] = v;
  }
}

// ---------------------------------------------------------------- causal flash attention
// grid 512, 512 threads (8 waves). One q-tile (128 rows) per block — the
// best-measured structure (R3: 98.1 us), kept EXACTLY. Structural ledger
// (all measured, all worse): 4-wave blocks 125, (q,k)-split 110, defer-max
// 104, 1-barrier dbuf 102. Converged local minimum at 2 waves/SIMD.
// F&31 = (b,h) group (XCD pin: F%8 = g%8); u = F>>5: qt = u (u<8) else 23-u,
// pairing long+short diagonals across co-dispatched blocks. Each wave owns 16
// q-rows; waves fully above the diagonal skip compute (barriers stay
// unconditional). Q prescaled by 192^-0.5*log2e; V is (B,H,128,S) transposed
// so staging is b128-only, bank-uniform. Softmax reductions: DPP row
// all-reduce. Staging: STATIC register arrays (r9: dynamic idx -> scratch 13x).
#define LK 200
#define LV 72
#define LP 72
__global__ __launch_bounds__(512) void flash_k(const BF16* __restrict__ Qt, const BF16* __restrict__ Kt,
                                               const BF16* __restrict__ Vt, BF16* __restrict__ O) {
  __shared__ __align__(16) BF16 Ks[64*LK];    // K tile [kpos][d]        25.6 KB
  __shared__ __align__(16) BF16 Vs[128*LV];   // V^T tile [vd][kpos]     18.4 KB
  __shared__ __align__(16) BF16 Ps[8][16*LP]; // per-wave P [q16][kpos]  18.4 KB
  int tid = threadIdx.x, wave = tid >> 6, lane = tid & 63;
  int lr = lane & 15, quad = lane >> 4;
  int F = blockIdx.x;
  int g = F & 31, u = F >> 5;
  int qt = (u < 8) ? u : 23 - u;      // co-resident pairing: qt + (15-qt)
  int h = g & 15, b = g >> 4;
  const BF16* Qb = Qt + ((long)(b*16 + h) * 2048) * 192;
  const BF16* Kb = Kt + ((long)(b*16 + h) * 2048) * 192;
  const BF16* Vb = Vt + ((long)(b*16 + h) * 128) * 2048;
  const float NEG_INF = -__builtin_inff();

  // staging geometry: K 1536 chunks / 512 thr = 3; V 1024 chunks / 512 thr = 2
  int krow[3], kcol[3];
#pragma unroll
  for (int i = 0; i < 3; i++) {
    int c = tid + 512*i;
    krow[i] = c / 24; kcol[i] = (c % 24) * 8;
  }
  int vrow[2], vcol[2];
#pragma unroll
  for (int i = 0; i < 2; i++) {
    int c = tid + 512*i;
    vrow[i] = c >> 3; vcol[i] = (c & 7) * 8;
  }

  bf16x8 kreg[3], vreg[2];   // depth-1, statically indexed
  auto stage_load = [&](int k0) {
#pragma unroll
    for (int i = 0; i < 3; i++)
      kreg[i] = *(const bf16x8*)(Kb + (long)(k0 + krow[i])*192 + kcol[i]);
#pragma unroll
    for (int i = 0; i < 2; i++)
      vreg[i] = *(const bf16x8*)(Vb + (long)vrow[i]*2048 + k0 + vcol[i]);
  };
  auto stage_store = [&]() {
#pragma unroll
    for (int i = 0; i < 3; i++)
      *(bf16x8*)(Ks + krow[i]*LK + kcol[i]) = kreg[i];
#pragma unroll
    for (int i = 0; i < 2; i++)
      *(bf16x8*)(Vs + vrow[i]*LV + vcol[i]) = vreg[i];
  };

  {
    int q0 = qt * 128;
    int wq0 = q0 + wave*16;   // this wave's first q-row
    bf16x8 qf[6];
    {
      const BF16* qp = Qb + (long)(wq0 + lr) * 192 + quad*8;
#pragma unroll
      for (int f = 0; f < 6; f++) qf[f] = *(const bf16x8*)(qp + f*32);
    }
    float m_i[4], l_i[4];
#pragma unroll
    for (int r = 0; r < 4; r++) { m_i[r] = NEG_INF; l_i[r] = 0.f; }
    floatx4 o_acc[8] = {};
    int nk = 2*qt + 2;
    stage_load(0);
    for (int kt = 0; kt < nk; kt++) {
      __syncthreads();   // prev-iter LDS reads complete
      stage_store();
      __syncthreads();
      if (kt + 1 < nk) stage_load((kt + 1) * 64);  // prefetch overlaps compute
      if (kt*64 > wq0 + 15) continue;  // wave fully above diagonal (masked out)
      floatx4 st[4];
      __builtin_amdgcn_s_setprio(1);
#pragma unroll
      for (int t = 0; t < 4; t++) {
        floatx4 c = {};
#pragma unroll
        for (int f = 0; f < 6; f++) {
          bf16x8 kf = *(const bf16x8*)(Ks + (t*16+lr)*LK + f*32 + quad*8);
          c = __builtin_amdgcn_mfma_f32_16x16x32_bf16(qf[f], kf, c, 0, 0, 0);
        }
        st[t] = c;
      }
      __builtin_amdgcn_s_setprio(0);
      float mt[4];
#pragma unroll
      for (int r = 0; r < 4; r++) mt[r] = NEG_INF;
      if (kt*64 + 63 > wq0) { // diagonal k-tile for this wave: causal mask
        int rbase = wq0 + quad*4 - kt*64;  // row - kbase
#pragma unroll
        for (int t = 0; t < 4; t++) {
          int coff = t*16 + lr;
#pragma unroll
          for (int r = 0; r < 4; r++) {
            float sc = st[t][r];
            if (coff > rbase + r) sc = NEG_INF;
            st[t][r] = sc;
            mt[r] = fmaxf(mt[r], sc);
          }
        }
      } else {
#pragma unroll
        for (int t = 0; t < 4; t++)
#pragma unroll
          for (int r = 0; r < 4; r++) mt[r] = fmaxf(mt[r], st[t][r]);
      }
#pragma unroll
      for (int r = 0; r < 4; r++) mt[r] = row_allmax(mt[r]);
      float alpha[4], rsum[4];
#pragma unroll
      for (int r = 0; r < 4; r++) {
        float mn = fmaxf(m_i[r], mt[r]);
        alpha[r] = fast_exp2(m_i[r] - mn);
        m_i[r] = mn;
        rsum[r] = 0.f;
      }
#pragma unroll
      for (int t = 0; t < 4; t++)
#pragma unroll
        for (int r = 0; r < 4; r++) {
          float p = fast_exp2(st[t][r] - m_i[r]);
          st[t][r] = p;
          rsum[r] += p;
        }
#pragma unroll
      for (int r = 0; r < 4; r++) rsum[r] = row_allsum(rsum[r]);
#pragma unroll
      for (int r = 0; r < 4; r++) l_i[r] = l_i[r]*alpha[r] + rsum[r];
#pragma unroll
      for (int v = 0; v < 8; v++)
#pragma unroll
        for (int r = 0; r < 4; r++) o_acc[v][r] *= alpha[r];
      // P (C-layout) -> wave-private LDS -> A-layout (no barrier: wave-level ordering)
#pragma unroll
      for (int t = 0; t < 4; t++)
#pragma unroll
        for (int r = 0; r < 4; r++)
          Ps[wave][(quad*4 + r)*LP + t*16 + lr] = f2b(st[t][r]);
      __builtin_amdgcn_s_setprio(1);
#pragma unroll
      for (int kc = 0; kc < 2; kc++) {
        bf16x8 pa = *(const bf16x8*)(&Ps[wave][lr*LP + kc*32 + quad*8]);
#pragma unroll
        for (int v = 0; v < 8; v++) {
          bf16x8 vf = *(const bf16x8*)(&Vs[(v*16+lr)*LV + kc*32 + quad*8]);
          o_acc[v] = __builtin_amdgcn_mfma_f32_16x16x32_bf16(pa, vf, o_acc[v], 0, 0, 0);
        }
      }
      __builtin_amdgcn_s_setprio(0);
    }
    // epilogue: attn out (B,S,H*128) bf16
    long rowb = wq0 + quad*4;
#pragma unroll
    for (int v = 0; v < 8; v++)
#pragma unroll
      for (int r = 0; r < 4; r++) {
        long row = rowb + r;
        O[((long)b*2048 + row)*2048 + h*128 + v*16 + lr] = f2b(o_acc[v][r] / l_i[r]);
      }
  }
}

// ---------------------------------------------------------------- launch
extern "C" void kernel_launch(void* const* d_in, const int* in_sizes, int n_in,
                              void* d_out, int out_size, void* d_ws, size_t ws_size,
                              hipStream_t stream) {
  const float* hidden      = (const float*)d_in[0];
  const float* cosb        = (const float*)d_in[1];
  const float* sinb        = (const float*)d_in[2];
  const float* q_a_W       = (const float*)d_in[3];
  const float* q_a_norm_w  = (const float*)d_in[4];
  const float* q_b_W       = (const float*)d_in[5];
  const float* kv_a_W      = (const float*)d_in[6];
  const float* kv_a_norm_w = (const float*)d_in[7];
  const float* kv_b_W      = (const float*)d_in[8];
  const float* o_W         = (const float*)d_in[9];
  float* out = (float*)d_out;

  const int Mrows = 4096;

  char* ws = (char*)d_ws; size_t off = 0;
  auto alloc = [&](size_t bytes) -> void* {
    void* p = ws + off; off = (off + bytes + 255) & ~(size_t)255; return p;
  };
  BF16* hb    = (BF16*)alloc((size_t)4096*2048*2);
  BF16* Wqakv = (BF16*)alloc((size_t)2112*2048*2);   // rows 0..1536 = q_a_W, 1536..2112 = kv_a_W
  BF16* Wqb   = (BF16*)alloc((size_t)3072*1536*2);
  BF16* Wkvb  = (BF16*)alloc((size_t)4096*512*2);
  BF16* Wo    = (BF16*)alloc((size_t)2048*2048*2);
  float* qakv = (float*)alloc((size_t)4096*2112*4);  // cols 0..1536 = q_a out, 1536..2112 = ckv
  BF16* qan   = (BF16*)alloc((size_t)4096*1536*2);
  BF16* kvn   = (BF16*)alloc((size_t)4096*512*2);
  BF16* Qt    = (BF16*)alloc((size_t)2*16*2048*192*2);
  BF16* Kt    = (BF16*)alloc((size_t)2*16*2048*192*2);
  BF16* Vt    = (BF16*)alloc((size_t)2*16*128*2048*2); // transposed (B,H,128,S)
  BF16* attn  = (BF16*)alloc((size_t)4096*2048*2);

  CastArgs ca;
  ca.src[0] = hidden;  ca.dst[0] = hb;                 ca.n[0] = (long)4096*2048;
  ca.src[1] = q_a_W;   ca.dst[1] = Wqakv;              ca.n[1] = (long)1536*2048;
  ca.src[2] = kv_a_W;  ca.dst[2] = Wqakv + (long)1536*2048; ca.n[2] = (long)576*2048;
  ca.src[3] = q_b_W;   ca.dst[3] = Wqb;                ca.n[3] = (long)3072*1536;
  ca.src[4] = kv_b_W;  ca.dst[4] = Wkvb;               ca.n[4] = (long)4096*512;
  ca.src[5] = o_W;     ca.dst[5] = Wo;                 ca.n[5] = (long)2048*2048;
  cast_multi_k<<<dim3(1024, 6), dim3(256), 0, stream>>>(ca);

  // [q_a | ckv] = hidden @ [q_a_W | kv_a_W].T  (4096 x 2112, K=2048), fp32
  gemm0_k<<<dim3(17, 16), dim3(512), 0, stream>>>(hb, Wqakv, qakv, Mrows, 2112, 2048);

  // fused rmsnorms + k_rot RoPE
  norms_k<<<dim3(4096), dim3(256), 0, stream>>>(qakv, q_a_norm_w, kv_a_norm_w,
                                                cosb, sinb, qan, kvn, Kt);

  // q_b (RoPE+scale -> Qt) and kv_b (scatter -> Kt / Vt^T) in one launch
  gemm_qkv_k<<<dim3(896), dim3(512), 0, stream>>>(qan, Wqb, kvn, Wkvb, cosb, sinb, Qt, Kt, Vt);

  flash_k<<<dim3(512), dim3(512), 0, stream>>>(Qt, Kt, Vt, attn);

  // out = attn @ o_W.T (4096x2048, K=2048), fp32 -> d_out
  gemm0_k<<<dim3(16, 16), dim3(512), 0, stream>>>(attn, Wo, out, Mrows, 2048, 2048);
}